// Round 1
// baseline (1058.351 us; speedup 1.0000x reference)
//
#include <hip/hip_runtime.h>

// ---------------- problem constants ----------------
#define T_TOK 16384
#define DM    512
#define DFF   2048
#define NE    8
#define NP    16
#define KP    4
#define RANK  64
#define KR    256           // KP * RANK
#define EPSF  1e-8f

typedef unsigned short u16;
typedef __bf16 bf16x8 __attribute__((ext_vector_type(8)));
typedef float  f32x4  __attribute__((ext_vector_type(4)));
typedef unsigned short u16x8v __attribute__((ext_vector_type(8)));
typedef unsigned short u16x4v __attribute__((ext_vector_type(4)));

__device__ __forceinline__ u16 f2bf(float f) {
  unsigned int u = __builtin_bit_cast(unsigned int, f);
  u += 0x7fffu + ((u >> 16) & 1u);          // round-to-nearest-even
  return (u16)(u >> 16);
}

// ---------------- kernel 1: zero out + counters ----------------
__global__ void zero_kernel(float4* __restrict__ o4, int n4,
                            int* __restrict__ cnt, float* __restrict__ probsum) {
  int i = blockIdx.x * 256 + threadIdx.x;
  if (i < n4) o4[i] = make_float4(0.f, 0.f, 0.f, 0.f);
  if (i < NE) cnt[i] = 0;
  if (i >= NE && i < NE + NE * 64) probsum[i - NE] = 0.f;
}

// ---------------- kernel 2: primitive-bank softmax + top-4 ----------------
__global__ void compose_meta(const float* __restrict__ fc1, const float* __restrict__ fc2,
                             float* __restrict__ sw1, int* __restrict__ idx1,
                             float* __restrict__ sw2, int* __restrict__ idx2) {
  int tid = threadIdx.x;
  if (tid >= 16) return;
  const float* src = (tid < 8) ? fc1 : fc2;
  float* sw = (tid < 8) ? sw1 : sw2;
  int*  idx = (tid < 8) ? idx1 : idx2;
  int e = tid & 7;
  float wv[NP];
  float mx = -1e30f;
  for (int p = 0; p < NP; p++) { wv[p] = src[e * NP + p]; mx = fmaxf(mx, wv[p]); }
  float sum = 0.f;
  for (int p = 0; p < NP; p++) { wv[p] = __expf(wv[p] - mx); sum += wv[p]; }
  float inv = 1.f / sum;
  for (int p = 0; p < NP; p++) wv[p] *= inv;
  float tw[KP]; int ti[KP];
  for (int k = 0; k < KP; k++) {
    int best = 0; float bv = -1.f;
    for (int p = 0; p < NP; p++) if (wv[p] > bv) { bv = wv[p]; best = p; }
    tw[k] = bv; ti[k] = best; wv[best] = -2.f;
  }
  float ts = tw[0] + tw[1] + tw[2] + tw[3];
  float invt = 1.f / (ts + EPSF);
  for (int k = 0; k < KP; k++) {
    sw[e * KP + k] = sqrtf(tw[k] * invt + EPSF);
    idx[e * KP + k] = ti[k];
  }
}

// ---------------- kernel 3: build composed weights, (N,K) bf16 layouts ----------------
// W1[e][kr][d]  = A1[p1[k]][d][r]*s1   (B-op for u = x @ A1c)
// V1[e][f][kr]  = B1[p1[k]][r][f]*s1   (B-op for h = u @ B1c)
// W2[e][kr][f]  = A2[p2[k]][f][r]*s2   (B-op for t = h @ A2c)
// V2[e][d][kr]  = B2[p2[k]][r][d]*s2   (B-op for y = t @ B2c)
__global__ void build_weights(const float* __restrict__ A1, const float* __restrict__ B1,
                              const float* __restrict__ A2, const float* __restrict__ B2,
                              const float* __restrict__ sw1, const int* __restrict__ idx1,
                              const float* __restrict__ sw2, const int* __restrict__ idx2,
                              u16* __restrict__ W1, u16* __restrict__ V1,
                              u16* __restrict__ W2, u16* __restrict__ V2) {
  const int S1 = NE * KR * DM;    // 1048576
  const int S2 = NE * DFF * KR;   // 4194304
  const int S3 = NE * KR * DFF;   // 4194304
  const int S4 = NE * DM * KR;    // 1048576
  int i = blockIdx.x * 256 + threadIdx.x;
  if (i >= S1 + S2 + S3 + S4) return;
  if (i < S1) {
    int d = i & (DM - 1); int kr = (i >> 9) & (KR - 1); int e = i >> 17;
    int k = kr >> 6, r = kr & 63; int p = idx1[e * 4 + k];
    W1[i] = f2bf(A1[((size_t)p * DM + d) * RANK + r] * sw1[e * 4 + k]);
  } else if (i < S1 + S2) {
    int j = i - S1;
    int kr = j & 255; int f = (j >> 8) & 2047; int e = j >> 19;
    int k = kr >> 6, r = kr & 63; int p = idx1[e * 4 + k];
    V1[j] = f2bf(B1[((size_t)p * RANK + r) * DFF + f] * sw1[e * 4 + k]);
  } else if (i < S1 + S2 + S3) {
    int j = i - S1 - S2;
    int f = j & 2047; int kr = (j >> 11) & 255; int e = j >> 19;
    int k = kr >> 6, r = kr & 63; int p = idx2[e * 4 + k];
    W2[j] = f2bf(A2[((size_t)p * DFF + f) * RANK + r] * sw2[e * 4 + k]);
  } else {
    int j = i - S1 - S2 - S3;
    int kr = j & 255; int d = (j >> 8) & 511; int e = j >> 17;
    int k = kr >> 6, r = kr & 63; int p = idx2[e * 4 + k];
    V2[j] = f2bf(B2[((size_t)p * RANK + r) * DM + d] * sw2[e * 4 + k]);
  }
}

// ---------------- kernel 4: router (1 wave / token) ----------------
__global__ void router_kernel(const float* __restrict__ x, const float* __restrict__ Wr,
                              int* __restrict__ cnt, float* __restrict__ probsum,
                              int* __restrict__ perm, float* __restrict__ gate) {
  __shared__ float wr_s[NE * DM];
  int tid = threadIdx.x;
  for (int i = tid; i < NE * DM; i += 256) wr_s[i] = Wr[i];
  __syncthreads();
  int wv = tid >> 6, lane = tid & 63;
  int t = blockIdx.x * 4 + wv;
  const float* xp = x + (size_t)t * DM;
  float xv[8];
#pragma unroll
  for (int c = 0; c < 8; c++) xv[c] = xp[lane + 64 * c];
  float lg[NE];
#pragma unroll
  for (int ee = 0; ee < NE; ee++) {
    float s = 0.f;
#pragma unroll
    for (int c = 0; c < 8; c++) s += xv[c] * wr_s[ee * DM + lane + 64 * c];
#pragma unroll
    for (int off = 32; off > 0; off >>= 1) s += __shfl_xor(s, off, 64);
    lg[ee] = s;
  }
  if (lane == 0) {
    float mx = lg[0];
    for (int ee = 1; ee < NE; ee++) mx = fmaxf(mx, lg[ee]);
    float pe[NE]; float sum = 0.f;
    for (int ee = 0; ee < NE; ee++) { pe[ee] = __expf(lg[ee] - mx); sum += pe[ee]; }
    float inv = 1.f / sum;
    for (int ee = 0; ee < NE; ee++) pe[ee] *= inv;
    int i0 = 0;
    for (int ee = 1; ee < NE; ee++) if (pe[ee] > pe[i0]) i0 = ee;
    int i1 = (i0 == 0) ? 1 : 0;
    for (int ee = 0; ee < NE; ee++) if (ee != i0 && pe[ee] > pe[i1]) i1 = ee;
    float p0 = pe[i0], p1 = pe[i1];
    float gden = 1.f / (p0 + p1 + EPSF);
    int pos0 = atomicAdd(&cnt[i0], 1);
    perm[i0 * T_TOK + pos0] = t;
    int pos1 = atomicAdd(&cnt[i1], 1);
    perm[i1 * T_TOK + pos1] = t;
    gate[i0 * T_TOK + t] = p0 * gden;
    gate[i1 * T_TOK + t] = p1 * gden;
    int slot = blockIdx.x & 63;
    for (int ee = 0; ee < NE; ee++)
      atomicAdd(&probsum[ee * 64 + slot], pe[ee]);
  }
}

// ---------------- kernel 5: aux loss ----------------
__global__ void aux_kernel(const int* __restrict__ cnt, const float* __restrict__ probsum,
                           float* __restrict__ aux_out) {
  if (threadIdx.x != 0 || blockIdx.x != 0) return;
  float c[NE]; float cs = 0.f;
  for (int e = 0; e < NE; e++) { c[e] = (float)cnt[e]; cs += c[e]; }
  float aux = 0.f;
  for (int e = 0; e < NE; e++) {
    float ps = 0.f;
    for (int s = 0; s < 64; s++) ps += probsum[e * 64 + s];
    aux += (c[e] / (cs + EPSF)) * (ps / (float)T_TOK);
  }
  *aux_out = (float)NE * aux;
}

// ---------------- kernel 6: fused sparse FFN ----------------
// LDS map (u16 units):
//   US  [0,16896)      : u / t tile, 64 x 256, stride 264 (pad 8 -> 2-way-free b128)
//   G   [16896,35328)  : staging, max(256x72, 64x264) = 18432
//   HS  [35328,39936)  : x-chunk / h-chunk, 64 x 72
#define LDS_US 0
#define LDS_G  16896
#define LDS_HS 35328
#define LDS_TOT 39936

__global__ __launch_bounds__(256, 2) void ffn_kernel(
    const float* __restrict__ x, const int* __restrict__ cnt,
    const int* __restrict__ perm, const float* __restrict__ gate,
    const u16* __restrict__ W1, const u16* __restrict__ V1,
    const u16* __restrict__ W2, const u16* __restrict__ V2,
    float* __restrict__ out) {
  __shared__ u16 lds[LDS_TOT];
  __shared__ int tok_s[64];
  __shared__ float g_s[64];

  int e = blockIdx.x >> 8;
  int tile = blockIdx.x & 255;
  int m0 = tile << 6;
  int cntE = cnt[e];
  if (m0 >= cntE) return;
  int Mt = cntE - m0; if (Mt > 64) Mt = 64;

  int tid = threadIdx.x;
  if (tid < 64) {
    int mm = (tid < Mt) ? tid : (Mt - 1);
    int tk = perm[e * T_TOK + m0 + mm];
    tok_s[tid] = tk;
    g_s[tid] = (tid < Mt) ? gate[e * T_TOK + tk] : 0.f;
  }
  __syncthreads();

  const u16* W1e = W1 + (size_t)e * KR * DM;
  const u16* V1e = V1 + (size_t)e * DFF * KR;
  const u16* W2e = W2 + (size_t)e * KR * DFF;
  const u16* V2e = V2 + (size_t)e * DM * KR;

  int w = tid >> 6;
  int ln = tid & 15;
  int quad = (tid >> 4) & 3;
  const f32x4 zero4 = {0.f, 0.f, 0.f, 0.f};

  // ======== phase 1: u = x_tile @ A1c  (64 x 256) ========
  f32x4 uacc[4][4];
#pragma unroll
  for (int a = 0; a < 4; a++)
#pragma unroll
    for (int b = 0; b < 4; b++) uacc[a][b] = zero4;

  for (int k0 = 0; k0 < DM; k0 += 64) {
    // gather x rows (fp32 -> bf16) into HS
    for (int c = tid; c < 1024; c += 256) {
      int m = c >> 4, cc = c & 15;
      float4 v = *(const float4*)(x + (size_t)tok_s[m] * DM + k0 + cc * 4);
      u16x4v o; o[0] = f2bf(v.x); o[1] = f2bf(v.y); o[2] = f2bf(v.z); o[3] = f2bf(v.w);
      *(u16x4v*)&lds[LDS_HS + m * 72 + cc * 4] = o;
    }
    // stage W1 chunk (256 rows x 64 k) into G, stride 72
    for (int c = tid; c < 2048; c += 256) {
      int n = c >> 3, cc = c & 7;
      *(u16x8v*)&lds[LDS_G + n * 72 + cc * 8] =
          *(const u16x8v*)(W1e + (size_t)n * DM + k0 + cc * 8);
    }
    __syncthreads();
#pragma unroll
    for (int ks = 0; ks < 2; ks++) {
      bf16x8 af[4], bfr[4];
#pragma unroll
      for (int mt = 0; mt < 4; mt++)
        af[mt] = *(const bf16x8*)&lds[LDS_HS + (mt * 16 + ln) * 72 + ks * 32 + quad * 8];
#pragma unroll
      for (int nt = 0; nt < 4; nt++)
        bfr[nt] = *(const bf16x8*)&lds[LDS_G + (w * 64 + nt * 16 + ln) * 72 + ks * 32 + quad * 8];
#pragma unroll
      for (int mt = 0; mt < 4; mt++)
#pragma unroll
        for (int nt = 0; nt < 4; nt++)
          uacc[mt][nt] = __builtin_amdgcn_mfma_f32_16x16x32_bf16(af[mt], bfr[nt], uacc[mt][nt], 0, 0, 0);
    }
    __syncthreads();
  }
  // write u -> US (bf16)   C/D layout: row = quad*4+reg, col = lane&15
#pragma unroll
  for (int mt = 0; mt < 4; mt++)
#pragma unroll
    for (int nt = 0; nt < 4; nt++)
#pragma unroll
      for (int r = 0; r < 4; r++) {
        int row = mt * 16 + quad * 4 + r;
        int col = w * 64 + nt * 16 + ln;
        lds[LDS_US + row * 264 + col] = f2bf(uacc[mt][nt][r]);
      }

  // ======== phase 2+3: t = gelu(u @ B1c) @ A2c  (64 x 256), Dff swept in 64-chunks ========
  f32x4 tacc[4][4];
#pragma unroll
  for (int a = 0; a < 4; a++)
#pragma unroll
    for (int b = 0; b < 4; b++) tacc[a][b] = zero4;

  for (int f0 = 0; f0 < DFF; f0 += 64) {
    __syncthreads();
    // stage V1 rows f0..f0+63 (64 x 256) into G, stride 264
    for (int c = tid; c < 2048; c += 256) {
      int r = c >> 5, cc = c & 31;
      *(u16x8v*)&lds[LDS_G + r * 264 + cc * 8] =
          *(const u16x8v*)(V1e + (size_t)(f0 + r) * KR + cc * 8);
    }
    __syncthreads();
    f32x4 hacc[4];
#pragma unroll
    for (int a = 0; a < 4; a++) hacc[a] = zero4;
#pragma unroll
    for (int ks = 0; ks < 8; ks++) {
      bf16x8 b = *(const bf16x8*)&lds[LDS_G + (w * 16 + ln) * 264 + ks * 32 + quad * 8];
#pragma unroll
      for (int mt = 0; mt < 4; mt++) {
        bf16x8 a = *(const bf16x8*)&lds[LDS_US + (mt * 16 + ln) * 264 + ks * 32 + quad * 8];
        hacc[mt] = __builtin_amdgcn_mfma_f32_16x16x32_bf16(a, b, hacc[mt], 0, 0, 0);
      }
    }
    // gelu (sigmoid approx) -> HS as bf16
#pragma unroll
    for (int mt = 0; mt < 4; mt++)
#pragma unroll
      for (int r = 0; r < 4; r++) {
        float v = hacc[mt][r];
        float s = 1.f / (1.f + __expf(-1.702f * v));
        lds[LDS_HS + (mt * 16 + quad * 4 + r) * 72 + w * 16 + ln] = f2bf(v * s);
      }
    __syncthreads();
    // stage W2 chunk (256 rows x 64 f) into G, stride 72
    for (int c = tid; c < 2048; c += 256) {
      int n = c >> 3, cc = c & 7;
      *(u16x8v*)&lds[LDS_G + n * 72 + cc * 8] =
          *(const u16x8v*)(W2e + (size_t)n * DFF + f0 + cc * 8);
    }
    __syncthreads();
#pragma unroll
    for (int ks = 0; ks < 2; ks++) {
      bf16x8 af[4], bfr[4];
#pragma unroll
      for (int mt = 0; mt < 4; mt++)
        af[mt] = *(const bf16x8*)&lds[LDS_HS + (mt * 16 + ln) * 72 + ks * 32 + quad * 8];
#pragma unroll
      for (int nt = 0; nt < 4; nt++)
        bfr[nt] = *(const bf16x8*)&lds[LDS_G + (w * 64 + nt * 16 + ln) * 72 + ks * 32 + quad * 8];
#pragma unroll
      for (int mt = 0; mt < 4; mt++)
#pragma unroll
        for (int nt = 0; nt < 4; nt++)
          tacc[mt][nt] = __builtin_amdgcn_mfma_f32_16x16x32_bf16(af[mt], bfr[nt], tacc[mt][nt], 0, 0, 0);
    }
  }

  // ======== phase 4: y = t @ B2c (64 x 512), scatter with gate ========
  __syncthreads();
#pragma unroll
  for (int mt = 0; mt < 4; mt++)
#pragma unroll
    for (int nt = 0; nt < 4; nt++)
#pragma unroll
      for (int r = 0; r < 4; r++) {
        int row = mt * 16 + quad * 4 + r;
        int col = w * 64 + nt * 16 + ln;
        lds[LDS_US + row * 264 + col] = f2bf(tacc[mt][nt][r]);
      }

  for (int n0 = 0; n0 < DM; n0 += 64) {
    __syncthreads();
    // stage V2 rows n0..n0+63 (64 x 256) into G, stride 264
    for (int c = tid; c < 2048; c += 256) {
      int r = c >> 5, cc = c & 31;
      *(u16x8v*)&lds[LDS_G + r * 264 + cc * 8] =
          *(const u16x8v*)(V2e + (size_t)(n0 + r) * KR + cc * 8);
    }
    __syncthreads();
    f32x4 yacc[4];
#pragma unroll
    for (int a = 0; a < 4; a++) yacc[a] = zero4;
#pragma unroll
    for (int ks = 0; ks < 8; ks++) {
      bf16x8 b = *(const bf16x8*)&lds[LDS_G + (w * 16 + ln) * 264 + ks * 32 + quad * 8];
#pragma unroll
      for (int mt = 0; mt < 4; mt++) {
        bf16x8 a = *(const bf16x8*)&lds[LDS_US + (mt * 16 + ln) * 264 + ks * 32 + quad * 8];
        yacc[mt] = __builtin_amdgcn_mfma_f32_16x16x32_bf16(a, b, yacc[mt], 0, 0, 0);
      }
    }
#pragma unroll
    for (int mt = 0; mt < 4; mt++)
#pragma unroll
      for (int r = 0; r < 4; r++) {
        int row = mt * 16 + quad * 4 + r;
        if (row < Mt) {
          int col = n0 + w * 16 + ln;
          atomicAdd(out + (size_t)tok_s[row] * DM + col, yacc[mt][r] * g_s[row]);
        }
      }
  }
}

// ---------------- launch ----------------
extern "C" void kernel_launch(void* const* d_in, const int* in_sizes, int n_in,
                              void* d_out, int out_size, void* d_ws, size_t ws_size,
                              hipStream_t stream) {
  const float* x   = (const float*)d_in[0];
  const float* Wr  = (const float*)d_in[1];
  const float* fc1 = (const float*)d_in[2];
  const float* fc2 = (const float*)d_in[3];
  const float* A1  = (const float*)d_in[4];
  const float* B1  = (const float*)d_in[5];
  const float* A2  = (const float*)d_in[6];
  const float* B2  = (const float*)d_in[7];
  float* out = (float*)d_out;

  char* ws = (char*)d_ws;
  float* sw1     = (float*)(ws + 0);
  int*   idx1    = (int*)(ws + 128);
  float* sw2     = (float*)(ws + 256);
  int*   idx2    = (int*)(ws + 384);
  int*   cnt     = (int*)(ws + 512);
  float* probsum = (float*)(ws + 576);          // 8 x 64 slots
  float* gate    = (float*)(ws + 4096);         // 8 x 16384
  int*   perm    = (int*)(ws + 4096 + 524288);  // 8 x 16384
  u16*   W1      = (u16*)(ws + 4096 + 2 * 524288);
  u16*   V1      = W1 + 1048576;
  u16*   W2      = V1 + 4194304;
  u16*   V2      = W2 + 4194304;
  // total ws use: ~22.0 MB

  int n4 = out_size >> 2;  // zeroes out[0 .. 8388608); aux slot written by aux_kernel
  zero_kernel<<<(n4 + 255) / 256, 256, 0, stream>>>((float4*)d_out, n4, cnt, probsum);
  compose_meta<<<1, 64, 0, stream>>>(fc1, fc2, sw1, idx1, sw2, idx2);
  build_weights<<<40960, 256, 0, stream>>>(A1, B1, A2, B2, sw1, idx1, sw2, idx2, W1, V1, W2, V2);
  router_kernel<<<T_TOK / 4, 256, 0, stream>>>(x, Wr, cnt, probsum, perm, gate);
  aux_kernel<<<1, 64, 0, stream>>>(cnt, probsum, out + (out_size - 1));
  ffn_kernel<<<NE * 256, 256, 0, stream>>>(x, cnt, perm, gate, W1, V1, W2, V2, out);
}

// Round 3
// 974.736 us; speedup vs baseline: 1.0858x; 1.0858x over previous
//
#include <hip/hip_runtime.h>

// ---------------- problem constants ----------------
#define T_TOK 16384
#define DM    512
#define DFF   2048
#define NE    8
#define NP    16
#define KP    4
#define RANK  64
#define KR    256           // KP * RANK
#define EPSF  1e-8f
#define CAP   6144          // per-expert pair capacity (expected ~4096)
#define MT_E  48            // CAP / 128 M-tiles per expert

typedef unsigned short u16;
typedef __bf16 bf16x8 __attribute__((ext_vector_type(8)));
typedef float  f32x4  __attribute__((ext_vector_type(4)));
typedef unsigned short u16x8v __attribute__((ext_vector_type(8)));
typedef unsigned short u16x4v __attribute__((ext_vector_type(4)));

typedef __attribute__((address_space(3))) void as3_void;
typedef __attribute__((address_space(1))) void as1_void;

__device__ __forceinline__ u16 f2bf(float f) {
  unsigned int u = __builtin_bit_cast(unsigned int, f);
  u += 0x7fffu + ((u >> 16) & 1u);          // round-to-nearest-even
  return (u16)(u >> 16);
}

__device__ __forceinline__ void gl_lds16(const u16* g, u16* l) {
  __builtin_amdgcn_global_load_lds((as1_void*)g, (as3_void*)l, 16, 0, 0);
}

// stage a 128x64 bf16 tile (row-major, row stride ld elems) into LDS (contig 128x64)
// per-wave lds dst = wave-uniform base + lane*16B (verified contiguous: elem off = ri*2048 + 512*w + 8*l)
__device__ __forceinline__ void stage_tile(const u16* g, int ld, u16* lds_tile, int tid) {
  int row = tid >> 3, c8 = (tid & 7) * 8;
#pragma unroll
  for (int ri = 0; ri < 4; ri++)
    gl_lds16(g + (size_t)(ri * 32 + row) * ld + c8, &lds_tile[(ri * 32 + row) * 64 + c8]);
}

// the shared 128x128 MFMA inner step over one BK=64 LDS tile pair
__device__ __forceinline__ void mfma_block(const u16* As, const u16* Bs, f32x4 acc[4][4],
                                           int wm, int wn, int ln, int quad) {
#pragma unroll
  for (int ks = 0; ks < 2; ks++) {
    bf16x8 af[4], bf[4];
#pragma unroll
    for (int mt = 0; mt < 4; mt++)
      af[mt] = *(const bf16x8*)&As[(wm * 64 + mt * 16 + ln) * 64 + ks * 32 + quad * 8];
#pragma unroll
    for (int nt = 0; nt < 4; nt++)
      bf[nt] = *(const bf16x8*)&Bs[(wn * 64 + nt * 16 + ln) * 64 + ks * 32 + quad * 8];
#pragma unroll
    for (int mt = 0; mt < 4; mt++)
#pragma unroll
      for (int nt = 0; nt < 4; nt++)
        acc[mt][nt] = __builtin_amdgcn_mfma_f32_16x16x32_bf16(af[mt], bf[nt], acc[mt][nt], 0, 0, 0);
  }
}

// ---------------- kernel 1: zero out + counters ----------------
__global__ void zero_kernel(float4* __restrict__ o4, int n4,
                            int* __restrict__ cnt, float* __restrict__ probsum) {
  int i = blockIdx.x * 256 + threadIdx.x;
  if (i < n4) o4[i] = make_float4(0.f, 0.f, 0.f, 0.f);
  if (i < NE) cnt[i] = 0;
  if (i >= NE && i < NE + NE * 64) probsum[i - NE] = 0.f;
}

// ---------------- kernel 2: primitive-bank softmax + top-4 ----------------
__global__ void compose_meta(const float* __restrict__ fc1, const float* __restrict__ fc2,
                             float* __restrict__ sw1, int* __restrict__ idx1,
                             float* __restrict__ sw2, int* __restrict__ idx2) {
  int tid = threadIdx.x;
  if (tid >= 16) return;
  const float* src = (tid < 8) ? fc1 : fc2;
  float* sw = (tid < 8) ? sw1 : sw2;
  int*  idx = (tid < 8) ? idx1 : idx2;
  int e = tid & 7;
  float wv[NP];
  float mx = -1e30f;
  for (int p = 0; p < NP; p++) { wv[p] = src[e * NP + p]; mx = fmaxf(mx, wv[p]); }
  float sum = 0.f;
  for (int p = 0; p < NP; p++) { wv[p] = __expf(wv[p] - mx); sum += wv[p]; }
  float inv = 1.f / sum;
  for (int p = 0; p < NP; p++) wv[p] *= inv;
  float tw[KP]; int ti[KP];
  for (int k = 0; k < KP; k++) {
    int best = 0; float bv = -1.f;
    for (int p = 0; p < NP; p++) if (wv[p] > bv) { bv = wv[p]; best = p; }
    tw[k] = bv; ti[k] = best; wv[best] = -2.f;
  }
  float ts = tw[0] + tw[1] + tw[2] + tw[3];
  float invt = 1.f / (ts + EPSF);
  for (int k = 0; k < KP; k++) {
    sw[e * KP + k] = sqrtf(tw[k] * invt + EPSF);
    idx[e * KP + k] = ti[k];
  }
}

// ---------------- kernel 3: build composed weights, (N,K) bf16 layouts ----------------
__global__ void build_weights(const float* __restrict__ A1, const float* __restrict__ B1,
                              const float* __restrict__ A2, const float* __restrict__ B2,
                              const float* __restrict__ sw1, const int* __restrict__ idx1,
                              const float* __restrict__ sw2, const int* __restrict__ idx2,
                              u16* __restrict__ W1, u16* __restrict__ V1,
                              u16* __restrict__ W2, u16* __restrict__ V2) {
  const int S1 = NE * KR * DM;    // 1048576
  const int S2 = NE * DFF * KR;   // 4194304
  const int S3 = NE * KR * DFF;   // 4194304
  const int S4 = NE * DM * KR;    // 1048576
  int i = blockIdx.x * 256 + threadIdx.x;
  if (i >= S1 + S2 + S3 + S4) return;
  if (i < S1) {
    int d = i & (DM - 1); int kr = (i >> 9) & (KR - 1); int e = i >> 17;
    int k = kr >> 6, r = kr & 63; int p = idx1[e * 4 + k];
    W1[i] = f2bf(A1[((size_t)p * DM + d) * RANK + r] * sw1[e * 4 + k]);
  } else if (i < S1 + S2) {
    int j = i - S1;
    int kr = j & 255; int f = (j >> 8) & 2047; int e = j >> 19;
    int k = kr >> 6, r = kr & 63; int p = idx1[e * 4 + k];
    V1[j] = f2bf(B1[((size_t)p * RANK + r) * DFF + f] * sw1[e * 4 + k]);
  } else if (i < S1 + S2 + S3) {
    int j = i - S1 - S2;
    int f = j & 2047; int kr = (j >> 11) & 255; int e = j >> 19;
    int k = kr >> 6, r = kr & 63; int p = idx2[e * 4 + k];
    W2[j] = f2bf(A2[((size_t)p * DFF + f) * RANK + r] * sw2[e * 4 + k]);
  } else {
    int j = i - S1 - S2 - S3;
    int kr = j & 255; int d = (j >> 8) & 511; int e = j >> 17;
    int k = kr >> 6, r = kr & 63; int p = idx2[e * 4 + k];
    V2[j] = f2bf(B2[((size_t)p * RANK + r) * DM + d] * sw2[e * 4 + k]);
  }
}

// ---------------- kernel 4: router (1 wave / token) ----------------
__global__ void router_kernel(const float* __restrict__ x, const float* __restrict__ Wr,
                              int* __restrict__ cnt, float* __restrict__ probsum,
                              int* __restrict__ perm, float* __restrict__ gate) {
  __shared__ float wr_s[NE * DM];
  int tid = threadIdx.x;
  for (int i = tid; i < NE * DM; i += 256) wr_s[i] = Wr[i];
  __syncthreads();
  int wv = tid >> 6, lane = tid & 63;
  int t = blockIdx.x * 4 + wv;
  const float* xp = x + (size_t)t * DM;
  float xv[8];
#pragma unroll
  for (int c = 0; c < 8; c++) xv[c] = xp[lane + 64 * c];
  float lg[NE];
#pragma unroll
  for (int ee = 0; ee < NE; ee++) {
    float s = 0.f;
#pragma unroll
    for (int c = 0; c < 8; c++) s += xv[c] * wr_s[ee * DM + lane + 64 * c];
#pragma unroll
    for (int off = 32; off > 0; off >>= 1) s += __shfl_xor(s, off, 64);
    lg[ee] = s;
  }
  if (lane == 0) {
    float mx = lg[0];
    for (int ee = 1; ee < NE; ee++) mx = fmaxf(mx, lg[ee]);
    float pe[NE]; float sum = 0.f;
    for (int ee = 0; ee < NE; ee++) { pe[ee] = __expf(lg[ee] - mx); sum += pe[ee]; }
    float inv = 1.f / sum;
    for (int ee = 0; ee < NE; ee++) pe[ee] *= inv;
    int i0 = 0;
    for (int ee = 1; ee < NE; ee++) if (pe[ee] > pe[i0]) i0 = ee;
    int i1 = (i0 == 0) ? 1 : 0;
    for (int ee = 0; ee < NE; ee++) if (ee != i0 && pe[ee] > pe[i1]) i1 = ee;
    float p0 = pe[i0], p1 = pe[i1];
    float gden = 1.f / (p0 + p1 + EPSF);
    int pos0 = atomicAdd(&cnt[i0], 1);
    perm[i0 * T_TOK + pos0] = t;
    int pos1 = atomicAdd(&cnt[i1], 1);
    perm[i1 * T_TOK + pos1] = t;
    gate[i0 * T_TOK + t] = p0 * gden;
    gate[i1 * T_TOK + t] = p1 * gden;
    int slot = blockIdx.x & 63;
    for (int ee = 0; ee < NE; ee++)
      atomicAdd(&probsum[ee * 64 + slot], pe[ee]);
  }
}

// ---------------- kernel 5: aux loss (one wave) ----------------
__global__ void aux_kernel(const int* __restrict__ cnt, const float* __restrict__ probsum,
                           float* __restrict__ aux_out) {
  int lane = threadIdx.x;
  if (lane >= 64) return;
  float s[NE];
#pragma unroll
  for (int e = 0; e < NE; e++) {
    float v = probsum[e * 64 + lane];
#pragma unroll
    for (int off = 32; off > 0; off >>= 1) v += __shfl_xor(v, off, 64);
    s[e] = v;
  }
  if (lane == 0) {
    float c[NE]; float cs = 0.f;
    for (int e = 0; e < NE; e++) { c[e] = (float)cnt[e]; cs += c[e]; }
    float aux = 0.f;
    for (int e = 0; e < NE; e++)
      aux += (c[e] / (cs + EPSF)) * (s[e] / (float)T_TOK);
    *aux_out = (float)NE * aux;
  }
}

// ================= split-pipeline GEMM kernels =================
// K1: u[slot,256] = bf16( gather(x) @ A1c )          B = W1 (256,512)
__global__ __launch_bounds__(256) void k1_u(
    const float* __restrict__ x, const int* __restrict__ cnt,
    const int* __restrict__ perm, const u16* __restrict__ W1,
    u16* __restrict__ u) {
  __shared__ __align__(16) u16 As[8192], Bs[8192];
  __shared__ int tok_s[128];
  int bid = blockIdx.x;
  int ntile = bid & 1, gm = bid >> 1;
  int e = gm / MT_E, mt = gm % MT_E;
  int m0 = mt << 7;
  int cntE = cnt[e];
  if (m0 >= cntE) return;
  int tid = threadIdx.x;
  if (tid < 128) {
    int mm = m0 + tid; if (mm > cntE - 1) mm = cntE - 1;
    tok_s[tid] = perm[e * T_TOK + mm];
  }
  __syncthreads();
  const u16* Bbase = W1 + (size_t)e * KR * DM + (size_t)(ntile * 128) * DM;
  int wv = tid >> 6, lane = tid & 63;
  int wm = wv >> 1, wn = wv & 1, ln = lane & 15, quad = lane >> 4;
  f32x4 acc[4][4];
#pragma unroll
  for (int a = 0; a < 4; a++)
#pragma unroll
    for (int b = 0; b < 4; b++) acc[a][b] = (f32x4){0.f, 0.f, 0.f, 0.f};
  for (int k0 = 0; k0 < DM; k0 += 64) {
    for (int i = tid; i < 2048; i += 256) {
      int row = i >> 4, c4 = i & 15;
      float4 v = *(const float4*)(x + (size_t)tok_s[row] * DM + k0 + c4 * 4);
      u16x4v o; o[0] = f2bf(v.x); o[1] = f2bf(v.y); o[2] = f2bf(v.z); o[3] = f2bf(v.w);
      *(u16x4v*)&As[row * 64 + c4 * 4] = o;
    }
    stage_tile(Bbase + k0, DM, Bs, tid);
    __syncthreads();
    mfma_block(As, Bs, acc, wm, wn, ln, quad);
    __syncthreads();
  }
  int slot0 = e * CAP + m0;
#pragma unroll
  for (int mt2 = 0; mt2 < 4; mt2++)
#pragma unroll
    for (int nt = 0; nt < 4; nt++)
#pragma unroll
      for (int r = 0; r < 4; r++) {
        int row = wm * 64 + mt2 * 16 + quad * 4 + r;
        int col = ntile * 128 + wn * 64 + nt * 16 + ln;
        u[(size_t)(slot0 + row) * KR + col] = f2bf(acc[mt2][nt][r]);
      }
}

// K2 (chunk c): h[slot, 512] = gelu( u @ B1c[:, c*512 : c*512+512] )   B = V1
__global__ __launch_bounds__(256) void k2_h(
    const u16* __restrict__ u, const int* __restrict__ cnt,
    const u16* __restrict__ V1, u16* __restrict__ h, int c) {
  __shared__ __align__(16) u16 As[8192], Bs[8192];
  int bid = blockIdx.x;
  int ntile = bid & 3, gm = bid >> 2;
  int e = gm / MT_E, mt = gm % MT_E;
  int m0 = mt << 7;
  int cntE = cnt[e];
  if (m0 >= cntE) return;
  int tid = threadIdx.x;
  int slot0 = e * CAP + m0;
  const u16* Abase = u + (size_t)slot0 * KR;
  const u16* Bbase = V1 + (size_t)e * DFF * KR + (size_t)(c * 512 + ntile * 128) * KR;
  int wv = tid >> 6, lane = tid & 63;
  int wm = wv >> 1, wn = wv & 1, ln = lane & 15, quad = lane >> 4;
  f32x4 acc[4][4];
#pragma unroll
  for (int a = 0; a < 4; a++)
#pragma unroll
    for (int b = 0; b < 4; b++) acc[a][b] = (f32x4){0.f, 0.f, 0.f, 0.f};
  for (int k0 = 0; k0 < KR; k0 += 64) {
    stage_tile(Abase + k0, KR, As, tid);
    stage_tile(Bbase + k0, KR, Bs, tid);
    __syncthreads();
    mfma_block(As, Bs, acc, wm, wn, ln, quad);
    __syncthreads();
  }
#pragma unroll
  for (int mt2 = 0; mt2 < 4; mt2++)
#pragma unroll
    for (int nt = 0; nt < 4; nt++)
#pragma unroll
      for (int r = 0; r < 4; r++) {
        int row = wm * 64 + mt2 * 16 + quad * 4 + r;
        int col = ntile * 128 + wn * 64 + nt * 16 + ln;
        float v = acc[mt2][nt][r];
        float s = 1.f / (1.f + __expf(-1.702f * v));
        h[(size_t)(slot0 + row) * 512 + col] = f2bf(v * s);
      }
}

// K3 (chunk c): t[slot,256] (+)= h @ A2c[c*512 : , :]    B = W2 cols c*512..
__global__ __launch_bounds__(256) void k3_t(
    const u16* __restrict__ h, const int* __restrict__ cnt,
    const u16* __restrict__ W2, float* __restrict__ t, int c, int beta) {
  __shared__ __align__(16) u16 As[8192], Bs[8192];
  int bid = blockIdx.x;
  int ntile = bid & 1, gm = bid >> 1;
  int e = gm / MT_E, mt = gm % MT_E;
  int m0 = mt << 7;
  int cntE = cnt[e];
  if (m0 >= cntE) return;
  int tid = threadIdx.x;
  int slot0 = e * CAP + m0;
  const u16* Abase = h + (size_t)slot0 * 512;
  const u16* Bbase = W2 + (size_t)e * KR * DFF + (size_t)(ntile * 128) * DFF + c * 512;
  int wv = tid >> 6, lane = tid & 63;
  int wm = wv >> 1, wn = wv & 1, ln = lane & 15, quad = lane >> 4;
  f32x4 acc[4][4];
#pragma unroll
  for (int a = 0; a < 4; a++)
#pragma unroll
    for (int b = 0; b < 4; b++) acc[a][b] = (f32x4){0.f, 0.f, 0.f, 0.f};
  for (int k0 = 0; k0 < 512; k0 += 64) {
    stage_tile(Abase + k0, 512, As, tid);
    stage_tile(Bbase + k0, DFF, Bs, tid);
    __syncthreads();
    mfma_block(As, Bs, acc, wm, wn, ln, quad);
    __syncthreads();
  }
#pragma unroll
  for (int mt2 = 0; mt2 < 4; mt2++)
#pragma unroll
    for (int nt = 0; nt < 4; nt++)
#pragma unroll
      for (int r = 0; r < 4; r++) {
        int row = wm * 64 + mt2 * 16 + quad * 4 + r;
        int col = ntile * 128 + wn * 64 + nt * 16 + ln;
        float* tp = t + (size_t)(slot0 + row) * KR + col;
        float v = acc[mt2][nt][r];
        if (beta) v += *tp;
        *tp = v;
      }
}

// K4: y = t @ B2c, scatter out[token] += gate * y      B = V2 (512,256)
__global__ __launch_bounds__(256) void k4_y(
    const float* __restrict__ t, const int* __restrict__ cnt,
    const int* __restrict__ perm, const float* __restrict__ gate,
    const u16* __restrict__ V2, float* __restrict__ out) {
  __shared__ __align__(16) u16 As[8192], Bs[8192];
  __shared__ int tok_s[128];
  __shared__ float g_s[128];
  int bid = blockIdx.x;
  int ntile = bid & 3, gm = bid >> 2;
  int e = gm / MT_E, mt = gm % MT_E;
  int m0 = mt << 7;
  int cntE = cnt[e];
  if (m0 >= cntE) return;
  int tid = threadIdx.x;
  if (tid < 128) {
    int mm = m0 + tid; if (mm > cntE - 1) mm = cntE - 1;
    int tk = perm[e * T_TOK + mm];
    tok_s[tid] = tk;
    g_s[tid] = gate[e * T_TOK + tk];
  }
  __syncthreads();
  int slot0 = e * CAP + m0;
  const float* Abase = t + (size_t)slot0 * KR;
  const u16* Bbase = V2 + (size_t)e * DM * KR + (size_t)(ntile * 128) * KR;
  int wv = tid >> 6, lane = tid & 63;
  int wm = wv >> 1, wn = wv & 1, ln = lane & 15, quad = lane >> 4;
  f32x4 acc[4][4];
#pragma unroll
  for (int a = 0; a < 4; a++)
#pragma unroll
    for (int b = 0; b < 4; b++) acc[a][b] = (f32x4){0.f, 0.f, 0.f, 0.f};
  for (int k0 = 0; k0 < KR; k0 += 64) {
    for (int i = tid; i < 2048; i += 256) {
      int row = i >> 4, c4 = i & 15;
      float4 v = *(const float4*)(Abase + (size_t)row * KR + k0 + c4 * 4);
      u16x4v o; o[0] = f2bf(v.x); o[1] = f2bf(v.y); o[2] = f2bf(v.z); o[3] = f2bf(v.w);
      *(u16x4v*)&As[row * 64 + c4 * 4] = o;
    }
    stage_tile(Bbase + k0, KR, Bs, tid);
    __syncthreads();
    mfma_block(As, Bs, acc, wm, wn, ln, quad);
    __syncthreads();
  }
#pragma unroll
  for (int mt2 = 0; mt2 < 4; mt2++)
#pragma unroll
    for (int nt = 0; nt < 4; nt++)
#pragma unroll
      for (int r = 0; r < 4; r++) {
        int row = wm * 64 + mt2 * 16 + quad * 4 + r;
        if (m0 + row < cntE) {
          int col = ntile * 128 + wn * 64 + nt * 16 + ln;
          atomicAdd(out + (size_t)tok_s[row] * DM + col, acc[mt2][nt][r] * g_s[row]);
        }
      }
}

// ---------------- fallback: round-1 fused FFN kernel ----------------
#define LDS_US 0
#define LDS_G  16896
#define LDS_HS 35328
#define LDS_TOT 39936

__global__ __launch_bounds__(256, 2) void ffn_kernel(
    const float* __restrict__ x, const int* __restrict__ cnt,
    const int* __restrict__ perm, const float* __restrict__ gate,
    const u16* __restrict__ W1, const u16* __restrict__ V1,
    const u16* __restrict__ W2, const u16* __restrict__ V2,
    float* __restrict__ out) {
  __shared__ __align__(16) u16 lds[LDS_TOT];
  __shared__ int tok_s[64];
  __shared__ float g_s[64];

  int e = blockIdx.x >> 8;
  int tile = blockIdx.x & 255;
  int m0 = tile << 6;
  int cntE = cnt[e];
  if (m0 >= cntE) return;
  int Mt = cntE - m0; if (Mt > 64) Mt = 64;

  int tid = threadIdx.x;
  if (tid < 64) {
    int mm = (tid < Mt) ? tid : (Mt - 1);
    int tk = perm[e * T_TOK + m0 + mm];
    tok_s[tid] = tk;
    g_s[tid] = (tid < Mt) ? gate[e * T_TOK + tk] : 0.f;
  }
  __syncthreads();

  const u16* W1e = W1 + (size_t)e * KR * DM;
  const u16* V1e = V1 + (size_t)e * DFF * KR;
  const u16* W2e = W2 + (size_t)e * KR * DFF;
  const u16* V2e = V2 + (size_t)e * DM * KR;

  int w = tid >> 6;
  int ln = tid & 15;
  int quad = (tid >> 4) & 3;
  const f32x4 zero4 = {0.f, 0.f, 0.f, 0.f};

  f32x4 uacc[4][4];
#pragma unroll
  for (int a = 0; a < 4; a++)
#pragma unroll
    for (int b = 0; b < 4; b++) uacc[a][b] = zero4;

  for (int k0 = 0; k0 < DM; k0 += 64) {
    for (int c = tid; c < 1024; c += 256) {
      int m = c >> 4, cc = c & 15;
      float4 v = *(const float4*)(x + (size_t)tok_s[m] * DM + k0 + cc * 4);
      u16x4v o; o[0] = f2bf(v.x); o[1] = f2bf(v.y); o[2] = f2bf(v.z); o[3] = f2bf(v.w);
      *(u16x4v*)&lds[LDS_HS + m * 72 + cc * 4] = o;
    }
    for (int c = tid; c < 2048; c += 256) {
      int n = c >> 3, cc = c & 7;
      *(u16x8v*)&lds[LDS_G + n * 72 + cc * 8] =
          *(const u16x8v*)(W1e + (size_t)n * DM + k0 + cc * 8);
    }
    __syncthreads();
#pragma unroll
    for (int ks = 0; ks < 2; ks++) {
      bf16x8 af[4], bfr[4];
#pragma unroll
      for (int mt = 0; mt < 4; mt++)
        af[mt] = *(const bf16x8*)&lds[LDS_HS + (mt * 16 + ln) * 72 + ks * 32 + quad * 8];
#pragma unroll
      for (int nt = 0; nt < 4; nt++)
        bfr[nt] = *(const bf16x8*)&lds[LDS_G + (w * 64 + nt * 16 + ln) * 72 + ks * 32 + quad * 8];
#pragma unroll
      for (int mt = 0; mt < 4; mt++)
#pragma unroll
        for (int nt = 0; nt < 4; nt++)
          uacc[mt][nt] = __builtin_amdgcn_mfma_f32_16x16x32_bf16(af[mt], bfr[nt], uacc[mt][nt], 0, 0, 0);
    }
    __syncthreads();
  }
#pragma unroll
  for (int mt = 0; mt < 4; mt++)
#pragma unroll
    for (int nt = 0; nt < 4; nt++)
#pragma unroll
      for (int r = 0; r < 4; r++) {
        int row = mt * 16 + quad * 4 + r;
        int col = w * 64 + nt * 16 + ln;
        lds[LDS_US + row * 264 + col] = f2bf(uacc[mt][nt][r]);
      }

  f32x4 tacc[4][4];
#pragma unroll
  for (int a = 0; a < 4; a++)
#pragma unroll
    for (int b = 0; b < 4; b++) tacc[a][b] = zero4;

  for (int f0 = 0; f0 < DFF; f0 += 64) {
    __syncthreads();
    for (int c = tid; c < 2048; c += 256) {
      int r = c >> 5, cc = c & 31;
      *(u16x8v*)&lds[LDS_G + r * 264 + cc * 8] =
          *(const u16x8v*)(V1e + (size_t)(f0 + r) * KR + cc * 8);
    }
    __syncthreads();
    f32x4 hacc[4];
#pragma unroll
    for (int a = 0; a < 4; a++) hacc[a] = zero4;
#pragma unroll
    for (int ks = 0; ks < 8; ks++) {
      bf16x8 b = *(const bf16x8*)&lds[LDS_G + (w * 16 + ln) * 264 + ks * 32 + quad * 8];
#pragma unroll
      for (int mt = 0; mt < 4; mt++) {
        bf16x8 a = *(const bf16x8*)&lds[LDS_US + (mt * 16 + ln) * 264 + ks * 32 + quad * 8];
        hacc[mt] = __builtin_amdgcn_mfma_f32_16x16x32_bf16(a, b, hacc[mt], 0, 0, 0);
      }
    }
#pragma unroll
    for (int mt = 0; mt < 4; mt++)
#pragma unroll
      for (int r = 0; r < 4; r++) {
        float v = hacc[mt][r];
        float s = 1.f / (1.f + __expf(-1.702f * v));
        lds[LDS_HS + (mt * 16 + quad * 4 + r) * 72 + w * 16 + ln] = f2bf(v * s);
      }
    __syncthreads();
    for (int c = tid; c < 2048; c += 256) {
      int n = c >> 3, cc = c & 7;
      *(u16x8v*)&lds[LDS_G + n * 72 + cc * 8] =
          *(const u16x8v*)(W2e + (size_t)n * DFF + f0 + cc * 8);
    }
    __syncthreads();
#pragma unroll
    for (int ks = 0; ks < 2; ks++) {
      bf16x8 af[4], bfr[4];
#pragma unroll
      for (int mt = 0; mt < 4; mt++)
        af[mt] = *(const bf16x8*)&lds[LDS_HS + (mt * 16 + ln) * 72 + ks * 32 + quad * 8];
#pragma unroll
      for (int nt = 0; nt < 4; nt++)
        bfr[nt] = *(const bf16x8*)&lds[LDS_G + (w * 64 + nt * 16 + ln) * 72 + ks * 32 + quad * 8];
#pragma unroll
      for (int mt = 0; mt < 4; mt++)
#pragma unroll
        for (int nt = 0; nt < 4; nt++)
          tacc[mt][nt] = __builtin_amdgcn_mfma_f32_16x16x32_bf16(af[mt], bfr[nt], tacc[mt][nt], 0, 0, 0);
    }
  }

  __syncthreads();
#pragma unroll
  for (int mt = 0; mt < 4; mt++)
#pragma unroll
    for (int nt = 0; nt < 4; nt++)
#pragma unroll
      for (int r = 0; r < 4; r++) {
        int row = mt * 16 + quad * 4 + r;
        int col = w * 64 + nt * 16 + ln;
        lds[LDS_US + row * 264 + col] = f2bf(tacc[mt][nt][r]);
      }

  for (int n0 = 0; n0 < DM; n0 += 64) {
    __syncthreads();
    for (int c = tid; c < 2048; c += 256) {
      int r = c >> 5, cc = c & 31;
      *(u16x8v*)&lds[LDS_G + r * 264 + cc * 8] =
          *(const u16x8v*)(V2e + (size_t)(n0 + r) * KR + cc * 8);
    }
    __syncthreads();
    f32x4 yacc[4];
#pragma unroll
    for (int a = 0; a < 4; a++) yacc[a] = zero4;
#pragma unroll
    for (int ks = 0; ks < 8; ks++) {
      bf16x8 b = *(const bf16x8*)&lds[LDS_G + (w * 16 + ln) * 264 + ks * 32 + quad * 8];
#pragma unroll
      for (int mt = 0; mt < 4; mt++) {
        bf16x8 a = *(const bf16x8*)&lds[LDS_US + (mt * 16 + ln) * 264 + ks * 32 + quad * 8];
        yacc[mt] = __builtin_amdgcn_mfma_f32_16x16x32_bf16(a, b, yacc[mt], 0, 0, 0);
      }
    }
#pragma unroll
    for (int mt = 0; mt < 4; mt++)
#pragma unroll
      for (int r = 0; r < 4; r++) {
        int row = mt * 16 + quad * 4 + r;
        if (row < Mt) {
          int col = n0 + w * 16 + ln;
          atomicAdd(out + (size_t)tok_s[row] * DM + col, yacc[mt][r] * g_s[row]);
        }
      }
  }
}

// ---------------- launch ----------------
extern "C" void kernel_launch(void* const* d_in, const int* in_sizes, int n_in,
                              void* d_out, int out_size, void* d_ws, size_t ws_size,
                              hipStream_t stream) {
  const float* x   = (const float*)d_in[0];
  const float* Wr  = (const float*)d_in[1];
  const float* fc1 = (const float*)d_in[2];
  const float* fc2 = (const float*)d_in[3];
  const float* A1  = (const float*)d_in[4];
  const float* B1  = (const float*)d_in[5];
  const float* A2  = (const float*)d_in[6];
  const float* B2  = (const float*)d_in[7];
  float* out = (float*)d_out;

  // ws layout — each meta array is 128 B (8 experts x 4 x 4 B); keep 512 B slots
  // (round-2 crash root cause: 64 B spacing overlapped sw1/idx1 -> garbage
  //  primitive index -> OOB global read -> aperture violation)
  char* ws = (char*)d_ws;
  float* sw1     = (float*)(ws + 0);
  int*   idx1    = (int*)(ws + 512);
  float* sw2     = (float*)(ws + 1024);
  int*   idx2    = (int*)(ws + 1536);
  int*   cnt     = (int*)(ws + 2048);
  float* probsum = (float*)(ws + 2560);         // 8 x 64 slots = 2048 B
  float* gate    = (float*)(ws + 8192);         // 8 x 16384 f32
  int*   perm    = (int*)(ws + 8192 + 524288);  // 8 x 16384 int
  u16*   W1      = (u16*)(ws + 8192 + 2 * 524288);
  u16*   V1      = W1 + 1048576;
  u16*   W2      = V1 + 4194304;
  u16*   V2      = W2 + 4194304;
  char*  endW    = (char*)(V2 + 1048576);       // ~22.0 MB
  u16*   u_buf   = (u16*)endW;                          // 49152 x 256 bf16 = 25.2 MB
  u16*   h_buf   = (u16*)(endW + 25165824);             // 49152 x 512 bf16 = 50.3 MB
  float* t_buf   = (float*)(endW + 25165824 + 50331648);// 49152 x 256 f32  = 50.3 MB
  const size_t WS_SPLIT_NEED = (size_t)(endW - ws) + 25165824ULL + 50331648ULL + 50331648ULL;

  int n4 = out_size >> 2;
  zero_kernel<<<(n4 + 255) / 256, 256, 0, stream>>>((float4*)d_out, n4, cnt, probsum);
  compose_meta<<<1, 64, 0, stream>>>(fc1, fc2, sw1, idx1, sw2, idx2);
  build_weights<<<40960, 256, 0, stream>>>(A1, B1, A2, B2, sw1, idx1, sw2, idx2, W1, V1, W2, V2);
  router_kernel<<<T_TOK / 4, 256, 0, stream>>>(x, Wr, cnt, probsum, perm, gate);
  aux_kernel<<<1, 64, 0, stream>>>(cnt, probsum, out + (out_size - 1));

  if (ws_size >= WS_SPLIT_NEED) {
    k1_u<<<2 * NE * MT_E, 256, 0, stream>>>(x, cnt, perm, W1, u_buf);
    for (int c = 0; c < 4; c++) {
      k2_h<<<4 * NE * MT_E, 256, 0, stream>>>(u_buf, cnt, V1, h_buf, c);
      k3_t<<<2 * NE * MT_E, 256, 0, stream>>>(h_buf, cnt, W2, t_buf, c, c > 0 ? 1 : 0);
    }
    k4_y<<<4 * NE * MT_E, 256, 0, stream>>>(t_buf, cnt, perm, gate, V2, out);
  } else {
    ffn_kernel<<<NE * 256, 256, 0, stream>>>(x, cnt, perm, gate, W1, V1, W2, V2, out);
  }
}

// Round 4
// 690.320 us; speedup vs baseline: 1.5331x; 1.4120x over previous
//
#include <hip/hip_runtime.h>

// ---------------- problem constants ----------------
#define T_TOK 16384
#define DM    512
#define DFF   2048
#define NE    8
#define NP    16
#define KP    4
#define RANK  64
#define KR    256           // KP * RANK
#define EPSF  1e-8f
#define CAP   6144          // per-expert pair capacity (expected ~4096)
#define MT_E  48            // CAP / 128 M-tiles per expert

typedef unsigned short u16;
typedef __bf16 bf16x8 __attribute__((ext_vector_type(8)));
typedef float  f32x4  __attribute__((ext_vector_type(4)));
typedef unsigned short u16x8v __attribute__((ext_vector_type(8)));
typedef unsigned short u16x4v __attribute__((ext_vector_type(4)));

typedef __attribute__((address_space(3))) void as3_void;
typedef __attribute__((address_space(1))) void as1_void;

__device__ __forceinline__ u16 f2bf(float f) {
  unsigned int u = __builtin_bit_cast(unsigned int, f);
  u += 0x7fffu + ((u >> 16) & 1u);          // round-to-nearest-even
  return (u16)(u >> 16);
}

__device__ __forceinline__ void gl_lds16(const u16* g, u16* l) {
  __builtin_amdgcn_global_load_lds((as1_void*)g, (as3_void*)l, 16, 0, 0);
}

// stage a 128x64 bf16 tile (row-major, row stride ld elems) into LDS (contig 128x64)
__device__ __forceinline__ void stage_tile(const u16* g, int ld, u16* lds_tile, int tid) {
  int row = tid >> 3, c8 = (tid & 7) * 8;
#pragma unroll
  for (int ri = 0; ri < 4; ri++)
    gl_lds16(g + (size_t)(ri * 32 + row) * ld + c8, &lds_tile[(ri * 32 + row) * 64 + c8]);
}

// the shared 128x128 MFMA inner step over one BK=64 LDS tile pair
__device__ __forceinline__ void mfma_block(const u16* As, const u16* Bs, f32x4 acc[4][4],
                                           int wm, int wn, int ln, int quad) {
#pragma unroll
  for (int ks = 0; ks < 2; ks++) {
    bf16x8 af[4], bf[4];
#pragma unroll
    for (int mt = 0; mt < 4; mt++)
      af[mt] = *(const bf16x8*)&As[(wm * 64 + mt * 16 + ln) * 64 + ks * 32 + quad * 8];
#pragma unroll
    for (int nt = 0; nt < 4; nt++)
      bf[nt] = *(const bf16x8*)&Bs[(wn * 64 + nt * 16 + ln) * 64 + ks * 32 + quad * 8];
#pragma unroll
    for (int mt = 0; mt < 4; mt++)
#pragma unroll
      for (int nt = 0; nt < 4; nt++)
        acc[mt][nt] = __builtin_amdgcn_mfma_f32_16x16x32_bf16(af[mt], bf[nt], acc[mt][nt], 0, 0, 0);
  }
}

// ---------------- kernel 1: zero out + counters ----------------
__global__ void zero_kernel(float4* __restrict__ o4, int n4,
                            int* __restrict__ cnt, float* __restrict__ probsum) {
  int i = blockIdx.x * 256 + threadIdx.x;
  if (i < n4) o4[i] = make_float4(0.f, 0.f, 0.f, 0.f);
  if (i < NE) cnt[i] = 0;
  if (i >= NE && i < NE + NE * 64) probsum[i - NE] = 0.f;
}

// ---------------- kernel 2: primitive-bank softmax + top-4 ----------------
__global__ void compose_meta(const float* __restrict__ fc1, const float* __restrict__ fc2,
                             float* __restrict__ sw1, int* __restrict__ idx1,
                             float* __restrict__ sw2, int* __restrict__ idx2) {
  int tid = threadIdx.x;
  if (tid >= 16) return;
  const float* src = (tid < 8) ? fc1 : fc2;
  float* sw = (tid < 8) ? sw1 : sw2;
  int*  idx = (tid < 8) ? idx1 : idx2;
  int e = tid & 7;
  float wv[NP];
  float mx = -1e30f;
  for (int p = 0; p < NP; p++) { wv[p] = src[e * NP + p]; mx = fmaxf(mx, wv[p]); }
  float sum = 0.f;
  for (int p = 0; p < NP; p++) { wv[p] = __expf(wv[p] - mx); sum += wv[p]; }
  float inv = 1.f / sum;
  for (int p = 0; p < NP; p++) wv[p] *= inv;
  float tw[KP]; int ti[KP];
  for (int k = 0; k < KP; k++) {
    int best = 0; float bv = -1.f;
    for (int p = 0; p < NP; p++) if (wv[p] > bv) { bv = wv[p]; best = p; }
    tw[k] = bv; ti[k] = best; wv[best] = -2.f;
  }
  float ts = tw[0] + tw[1] + tw[2] + tw[3];
  float invt = 1.f / (ts + EPSF);
  for (int k = 0; k < KP; k++) {
    sw[e * KP + k] = sqrtf(tw[k] * invt + EPSF);
    idx[e * KP + k] = ti[k];
  }
}

// ---------------- kernel 3: build composed weights, (N,K) bf16 layouts ----------------
__global__ void build_weights(const float* __restrict__ A1, const float* __restrict__ B1,
                              const float* __restrict__ A2, const float* __restrict__ B2,
                              const float* __restrict__ sw1, const int* __restrict__ idx1,
                              const float* __restrict__ sw2, const int* __restrict__ idx2,
                              u16* __restrict__ W1, u16* __restrict__ V1,
                              u16* __restrict__ W2, u16* __restrict__ V2) {
  const int S1 = NE * KR * DM;    // 1048576
  const int S2 = NE * DFF * KR;   // 4194304
  const int S3 = NE * KR * DFF;   // 4194304
  const int S4 = NE * DM * KR;    // 1048576
  int i = blockIdx.x * 256 + threadIdx.x;
  if (i >= S1 + S2 + S3 + S4) return;
  if (i < S1) {
    int d = i & (DM - 1); int kr = (i >> 9) & (KR - 1); int e = i >> 17;
    int k = kr >> 6, r = kr & 63; int p = idx1[e * 4 + k];
    W1[i] = f2bf(A1[((size_t)p * DM + d) * RANK + r] * sw1[e * 4 + k]);
  } else if (i < S1 + S2) {
    int j = i - S1;
    int kr = j & 255; int f = (j >> 8) & 2047; int e = j >> 19;
    int k = kr >> 6, r = kr & 63; int p = idx1[e * 4 + k];
    V1[j] = f2bf(B1[((size_t)p * RANK + r) * DFF + f] * sw1[e * 4 + k]);
  } else if (i < S1 + S2 + S3) {
    int j = i - S1 - S2;
    int f = j & 2047; int kr = (j >> 11) & 255; int e = j >> 19;
    int k = kr >> 6, r = kr & 63; int p = idx2[e * 4 + k];
    W2[j] = f2bf(A2[((size_t)p * DFF + f) * RANK + r] * sw2[e * 4 + k]);
  } else {
    int j = i - S1 - S2 - S3;
    int kr = j & 255; int d = (j >> 8) & 511; int e = j >> 17;
    int k = kr >> 6, r = kr & 63; int p = idx2[e * 4 + k];
    V2[j] = f2bf(B2[((size_t)p * RANK + r) * DM + d] * sw2[e * 4 + k]);
  }
}

// ---------------- kernel 4: router compute (1 wave / token, NO cnt atomics) ----------------
__global__ void router_kernel(const float* __restrict__ x, const float* __restrict__ Wr,
                              float* __restrict__ probsum, int* __restrict__ eidx,
                              float* __restrict__ gate) {
  __shared__ float wr_s[NE * DM];
  int tid = threadIdx.x;
  for (int i = tid; i < NE * DM; i += 256) wr_s[i] = Wr[i];
  __syncthreads();
  int wv = tid >> 6, lane = tid & 63;
  int t = blockIdx.x * 4 + wv;
  const float* xp = x + (size_t)t * DM;
  float xv[8];
#pragma unroll
  for (int c = 0; c < 8; c++) xv[c] = xp[lane + 64 * c];
  float lg[NE];
#pragma unroll
  for (int ee = 0; ee < NE; ee++) {
    float s = 0.f;
#pragma unroll
    for (int c = 0; c < 8; c++) s += xv[c] * wr_s[ee * DM + lane + 64 * c];
#pragma unroll
    for (int off = 32; off > 0; off >>= 1) s += __shfl_xor(s, off, 64);
    lg[ee] = s;
  }
  if (lane == 0) {
    float mx = lg[0];
    for (int ee = 1; ee < NE; ee++) mx = fmaxf(mx, lg[ee]);
    float pe[NE]; float sum = 0.f;
    for (int ee = 0; ee < NE; ee++) { pe[ee] = __expf(lg[ee] - mx); sum += pe[ee]; }
    float inv = 1.f / sum;
    for (int ee = 0; ee < NE; ee++) pe[ee] *= inv;
    int i0 = 0;
    for (int ee = 1; ee < NE; ee++) if (pe[ee] > pe[i0]) i0 = ee;
    int i1 = (i0 == 0) ? 1 : 0;
    for (int ee = 0; ee < NE; ee++) if (ee != i0 && pe[ee] > pe[i1]) i1 = ee;
    float p0 = pe[i0], p1 = pe[i1];
    float gden = 1.f / (p0 + p1 + EPSF);
    eidx[t] = i0 | (i1 << 3);
    gate[i0 * T_TOK + t] = p0 * gden;
    gate[i1 * T_TOK + t] = p1 * gden;
    int slot = blockIdx.x & 63;
    for (int ee = 0; ee < NE; ee++)
      atomicAdd(&probsum[ee * 64 + slot], pe[ee]);
  }
}

// ---------------- kernel 4b: scatter (block-aggregated cnt, 64 blocks x 256 tokens) ------
__global__ void scatter_kernel(const int* __restrict__ eidx,
                               int* __restrict__ cnt, int* __restrict__ perm) {
  __shared__ int hist[NE], base[NE];
  int tid = threadIdx.x;
  if (tid < NE) hist[tid] = 0;
  __syncthreads();
  int t = blockIdx.x * 256 + tid;
  int pk = eidx[t];
  int e0 = pk & 7, e1 = (pk >> 3) & 7;
  int p0 = atomicAdd(&hist[e0], 1);
  int p1 = atomicAdd(&hist[e1], 1);
  __syncthreads();
  if (tid < NE) base[tid] = atomicAdd(&cnt[tid], hist[tid]);
  __syncthreads();
  perm[e0 * T_TOK + base[e0] + p0] = t;
  perm[e1 * T_TOK + base[e1] + p1] = t;
}

// ---------------- kernel 5: aux loss (one wave) ----------------
__global__ void aux_kernel(const int* __restrict__ cnt, const float* __restrict__ probsum,
                           float* __restrict__ aux_out) {
  int lane = threadIdx.x;
  if (lane >= 64) return;
  float s[NE];
#pragma unroll
  for (int e = 0; e < NE; e++) {
    float v = probsum[e * 64 + lane];
#pragma unroll
    for (int off = 32; off > 0; off >>= 1) v += __shfl_xor(v, off, 64);
    s[e] = v;
  }
  if (lane == 0) {
    float c[NE]; float cs = 0.f;
    for (int e = 0; e < NE; e++) { c[e] = (float)cnt[e]; cs += c[e]; }
    float aux = 0.f;
    for (int e = 0; e < NE; e++)
      aux += (c[e] / (cs + EPSF)) * (s[e] / (float)T_TOK);
    *aux_out = (float)NE * aux;
  }
}

// ================= split-pipeline GEMM kernels =================
// K1: u[slot,256] = bf16( gather(x) @ A1c )          B = W1 (256,512)
__global__ __launch_bounds__(256) void k1_u(
    const float* __restrict__ x, const int* __restrict__ cnt,
    const int* __restrict__ perm, const u16* __restrict__ W1,
    u16* __restrict__ u) {
  __shared__ __align__(16) u16 As[8192], Bs[8192];
  __shared__ int tok_s[128];
  int bid = blockIdx.x;
  int ntile = bid & 1, gm = bid >> 1;
  int e = gm / MT_E, mt = gm % MT_E;
  int m0 = mt << 7;
  int cntE = cnt[e];
  if (m0 >= cntE) return;
  int tid = threadIdx.x;
  if (tid < 128) {
    int mm = m0 + tid; if (mm > cntE - 1) mm = cntE - 1;
    tok_s[tid] = perm[e * T_TOK + mm];
  }
  __syncthreads();
  const u16* Bbase = W1 + (size_t)e * KR * DM + (size_t)(ntile * 128) * DM;
  int wv = tid >> 6, lane = tid & 63;
  int wm = wv >> 1, wn = wv & 1, ln = lane & 15, quad = lane >> 4;
  f32x4 acc[4][4];
#pragma unroll
  for (int a = 0; a < 4; a++)
#pragma unroll
    for (int b = 0; b < 4; b++) acc[a][b] = (f32x4){0.f, 0.f, 0.f, 0.f};
  for (int k0 = 0; k0 < DM; k0 += 64) {
    for (int i = tid; i < 2048; i += 256) {
      int row = i >> 4, c4 = i & 15;
      float4 v = *(const float4*)(x + (size_t)tok_s[row] * DM + k0 + c4 * 4);
      u16x4v o; o[0] = f2bf(v.x); o[1] = f2bf(v.y); o[2] = f2bf(v.z); o[3] = f2bf(v.w);
      *(u16x4v*)&As[row * 64 + c4 * 4] = o;
    }
    stage_tile(Bbase + k0, DM, Bs, tid);
    __syncthreads();
    mfma_block(As, Bs, acc, wm, wn, ln, quad);
    __syncthreads();
  }
  int slot0 = e * CAP + m0;
#pragma unroll
  for (int mt2 = 0; mt2 < 4; mt2++)
#pragma unroll
    for (int nt = 0; nt < 4; nt++)
#pragma unroll
      for (int r = 0; r < 4; r++) {
        int row = wm * 64 + mt2 * 16 + quad * 4 + r;
        int col = ntile * 128 + wn * 64 + nt * 16 + ln;
        u[(size_t)(slot0 + row) * KR + col] = f2bf(acc[mt2][nt][r]);
      }
}

// K2 (chunk c): h[slot, 512] = gelu( u @ B1c[:, c*512 : c*512+512] )   B = V1
__global__ __launch_bounds__(256) void k2_h(
    const u16* __restrict__ u, const int* __restrict__ cnt,
    const u16* __restrict__ V1, u16* __restrict__ h, int c) {
  __shared__ __align__(16) u16 As[8192], Bs[8192];
  int bid = blockIdx.x;
  int ntile = bid & 3, gm = bid >> 2;
  int e = gm / MT_E, mt = gm % MT_E;
  int m0 = mt << 7;
  int cntE = cnt[e];
  if (m0 >= cntE) return;
  int tid = threadIdx.x;
  int slot0 = e * CAP + m0;
  const u16* Abase = u + (size_t)slot0 * KR;
  const u16* Bbase = V1 + (size_t)e * DFF * KR + (size_t)(c * 512 + ntile * 128) * KR;
  int wv = tid >> 6, lane = tid & 63;
  int wm = wv >> 1, wn = wv & 1, ln = lane & 15, quad = lane >> 4;
  f32x4 acc[4][4];
#pragma unroll
  for (int a = 0; a < 4; a++)
#pragma unroll
    for (int b = 0; b < 4; b++) acc[a][b] = (f32x4){0.f, 0.f, 0.f, 0.f};
  for (int k0 = 0; k0 < KR; k0 += 64) {
    stage_tile(Abase + k0, KR, As, tid);
    stage_tile(Bbase + k0, KR, Bs, tid);
    __syncthreads();
    mfma_block(As, Bs, acc, wm, wn, ln, quad);
    __syncthreads();
  }
#pragma unroll
  for (int mt2 = 0; mt2 < 4; mt2++)
#pragma unroll
    for (int nt = 0; nt < 4; nt++)
#pragma unroll
      for (int r = 0; r < 4; r++) {
        int row = wm * 64 + mt2 * 16 + quad * 4 + r;
        int col = ntile * 128 + wn * 64 + nt * 16 + ln;
        float v = acc[mt2][nt][r];
        float s = 1.f / (1.f + __expf(-1.702f * v));
        h[(size_t)(slot0 + row) * 512 + col] = f2bf(v * s);
      }
}

// K3 (chunk c): t[slot,256] (+)= h @ A2c[c*512 : , :]    B = W2 cols c*512..
__global__ __launch_bounds__(256) void k3_t(
    const u16* __restrict__ h, const int* __restrict__ cnt,
    const u16* __restrict__ W2, float* __restrict__ t, int c, int beta) {
  __shared__ __align__(16) u16 As[8192], Bs[8192];
  int bid = blockIdx.x;
  int ntile = bid & 1, gm = bid >> 1;
  int e = gm / MT_E, mt = gm % MT_E;
  int m0 = mt << 7;
  int cntE = cnt[e];
  if (m0 >= cntE) return;
  int tid = threadIdx.x;
  int slot0 = e * CAP + m0;
  const u16* Abase = h + (size_t)slot0 * 512;
  const u16* Bbase = W2 + (size_t)e * KR * DFF + (size_t)(ntile * 128) * DFF + c * 512;
  int wv = tid >> 6, lane = tid & 63;
  int wm = wv >> 1, wn = wv & 1, ln = lane & 15, quad = lane >> 4;
  f32x4 acc[4][4];
#pragma unroll
  for (int a = 0; a < 4; a++)
#pragma unroll
    for (int b = 0; b < 4; b++) acc[a][b] = (f32x4){0.f, 0.f, 0.f, 0.f};
  for (int k0 = 0; k0 < 512; k0 += 64) {
    stage_tile(Abase + k0, 512, As, tid);
    stage_tile(Bbase + k0, DFF, Bs, tid);
    __syncthreads();
    mfma_block(As, Bs, acc, wm, wn, ln, quad);
    __syncthreads();
  }
#pragma unroll
  for (int mt2 = 0; mt2 < 4; mt2++)
#pragma unroll
    for (int nt = 0; nt < 4; nt++)
#pragma unroll
      for (int r = 0; r < 4; r++) {
        int row = wm * 64 + mt2 * 16 + quad * 4 + r;
        int col = ntile * 128 + wn * 64 + nt * 16 + ln;
        float* tp = t + (size_t)(slot0 + row) * KR + col;
        float v = acc[mt2][nt][r];
        if (beta) v += *tp;
        *tp = v;
      }
}

// K4: y = t @ B2c, scatter out[token] += gate * y      B = V2 (512,256)
__global__ __launch_bounds__(256) void k4_y(
    const float* __restrict__ t, const int* __restrict__ cnt,
    const int* __restrict__ perm, const float* __restrict__ gate,
    const u16* __restrict__ V2, float* __restrict__ out) {
  __shared__ __align__(16) u16 As[8192], Bs[8192];
  __shared__ int tok_s[128];
  __shared__ float g_s[128];
  int bid = blockIdx.x;
  int ntile = bid & 3, gm = bid >> 2;
  int e = gm / MT_E, mt = gm % MT_E;
  int m0 = mt << 7;
  int cntE = cnt[e];
  if (m0 >= cntE) return;
  int tid = threadIdx.x;
  if (tid < 128) {
    int mm = m0 + tid; if (mm > cntE - 1) mm = cntE - 1;
    int tk = perm[e * T_TOK + mm];
    tok_s[tid] = tk;
    g_s[tid] = gate[e * T_TOK + tk];
  }
  __syncthreads();
  int slot0 = e * CAP + m0;
  const float* Abase = t + (size_t)slot0 * KR;
  const u16* Bbase = V2 + (size_t)e * DM * KR + (size_t)(ntile * 128) * KR;
  int wv = tid >> 6, lane = tid & 63;
  int wm = wv >> 1, wn = wv & 1, ln = lane & 15, quad = lane >> 4;
  f32x4 acc[4][4];
#pragma unroll
  for (int a = 0; a < 4; a++)
#pragma unroll
    for (int b = 0; b < 4; b++) acc[a][b] = (f32x4){0.f, 0.f, 0.f, 0.f};
  for (int k0 = 0; k0 < KR; k0 += 64) {
    for (int i = tid; i < 2048; i += 256) {
      int row = i >> 4, c4 = i & 15;
      float4 v = *(const float4*)(Abase + (size_t)row * KR + k0 + c4 * 4);
      u16x4v o; o[0] = f2bf(v.x); o[1] = f2bf(v.y); o[2] = f2bf(v.z); o[3] = f2bf(v.w);
      *(u16x4v*)&As[row * 64 + c4 * 4] = o;
    }
    stage_tile(Bbase + k0, KR, Bs, tid);
    __syncthreads();
    mfma_block(As, Bs, acc, wm, wn, ln, quad);
    __syncthreads();
  }
#pragma unroll
  for (int mt2 = 0; mt2 < 4; mt2++)
#pragma unroll
    for (int nt = 0; nt < 4; nt++)
#pragma unroll
      for (int r = 0; r < 4; r++) {
        int row = wm * 64 + mt2 * 16 + quad * 4 + r;
        if (m0 + row < cntE) {
          int col = ntile * 128 + wn * 64 + nt * 16 + ln;
          atomicAdd(out + (size_t)tok_s[row] * DM + col, acc[mt2][nt][r] * g_s[row]);
        }
      }
}

// ---------------- launch ----------------
extern "C" void kernel_launch(void* const* d_in, const int* in_sizes, int n_in,
                              void* d_out, int out_size, void* d_ws, size_t ws_size,
                              hipStream_t stream) {
  const float* x   = (const float*)d_in[0];
  const float* Wr  = (const float*)d_in[1];
  const float* fc1 = (const float*)d_in[2];
  const float* fc2 = (const float*)d_in[3];
  const float* A1  = (const float*)d_in[4];
  const float* B1  = (const float*)d_in[5];
  const float* A2  = (const float*)d_in[6];
  const float* B2  = (const float*)d_in[7];
  float* out = (float*)d_out;

  char* ws = (char*)d_ws;
  float* sw1     = (float*)(ws + 0);
  int*   idx1    = (int*)(ws + 512);
  float* sw2     = (float*)(ws + 1024);
  int*   idx2    = (int*)(ws + 1536);
  int*   cnt     = (int*)(ws + 2048);
  float* probsum = (float*)(ws + 2560);         // 8 x 64 slots = 2048 B
  int*   eidx    = (int*)(ws + 8192);           // 16384 int = 64 KB
  float* gate    = (float*)(ws + 8192 + 65536);           // 8 x 16384 f32
  int*   perm    = (int*)(ws + 8192 + 65536 + 524288);    // 8 x 16384 int
  u16*   W1      = (u16*)(ws + 8192 + 65536 + 2 * 524288);
  u16*   V1      = W1 + 1048576;
  u16*   W2      = V1 + 4194304;
  u16*   V2      = W2 + 4194304;
  char*  endW    = (char*)(V2 + 1048576);
  u16*   u_buf   = (u16*)endW;                          // 49152 x 256 bf16
  u16*   h_buf   = (u16*)(endW + 25165824);             // 49152 x 512 bf16
  float* t_buf   = (float*)(endW + 25165824 + 50331648);// 49152 x 256 f32
  const size_t WS_SPLIT_NEED = (size_t)(endW - ws) + 25165824ULL + 50331648ULL + 50331648ULL;

  int n4 = out_size >> 2;
  zero_kernel<<<(n4 + 255) / 256, 256, 0, stream>>>((float4*)d_out, n4, cnt, probsum);
  compose_meta<<<1, 64, 0, stream>>>(fc1, fc2, sw1, idx1, sw2, idx2);
  build_weights<<<40960, 256, 0, stream>>>(A1, B1, A2, B2, sw1, idx1, sw2, idx2, W1, V1, W2, V2);
  router_kernel<<<T_TOK / 4, 256, 0, stream>>>(x, Wr, probsum, eidx, gate);
  scatter_kernel<<<T_TOK / 256, 256, 0, stream>>>(eidx, cnt, perm);
  aux_kernel<<<1, 64, 0, stream>>>(cnt, probsum, out + (out_size - 1));

  if (ws_size >= WS_SPLIT_NEED) {
    k1_u<<<2 * NE * MT_E, 256, 0, stream>>>(x, cnt, perm, W1, u_buf);
    for (int c = 0; c < 4; c++) {
      k2_h<<<4 * NE * MT_E, 256, 0, stream>>>(u_buf, cnt, V1, h_buf, c);
      k3_t<<<2 * NE * MT_E, 256, 0, stream>>>(h_buf, cnt, W2, t_buf, c, c > 0 ? 1 : 0);
    }
    k4_y<<<4 * NE * MT_E, 256, 0, stream>>>(t_buf, cnt, perm, gate, V2, out);
  }
}

// Round 5
// 604.051 us; speedup vs baseline: 1.7521x; 1.1428x over previous
//
#include <hip/hip_runtime.h>

// ---------------- problem constants ----------------
#define T_TOK 16384
#define DM    512
#define DFF   2048
#define NE    8
#define NP    16
#define KP    4
#define RANK  64
#define KR    256           // KP * RANK
#define EPSF  1e-8f
#define CAP   6144          // per-expert pair capacity (expected ~4096)
#define MT_E  48            // CAP / 128 M-tiles per expert

typedef unsigned short u16;
typedef __bf16 bf16x8 __attribute__((ext_vector_type(8)));
typedef float  f32x4  __attribute__((ext_vector_type(4)));
typedef unsigned short u16x8v __attribute__((ext_vector_type(8)));
typedef unsigned short u16x4v __attribute__((ext_vector_type(4)));

typedef __attribute__((address_space(3))) void as3_void;
typedef __attribute__((address_space(1))) void as1_void;

__device__ __forceinline__ u16 f2bf(float f) {
  unsigned int u = __builtin_bit_cast(unsigned int, f);
  u += 0x7fffu + ((u >> 16) & 1u);          // round-to-nearest-even
  return (u16)(u >> 16);
}

__device__ __forceinline__ void gl_lds16(const u16* g, u16* l) {
  __builtin_amdgcn_global_load_lds((as1_void*)g, (as3_void*)l, 16, 0, 0);
}

// stage a 128x64 bf16 tile (row-major, row stride ld elems) into LDS (contig 128x64)
__device__ __forceinline__ void stage_tile(const u16* g, int ld, u16* lds_tile, int tid) {
  int row = tid >> 3, c8 = (tid & 7) * 8;
#pragma unroll
  for (int ri = 0; ri < 4; ri++)
    gl_lds16(g + (size_t)(ri * 32 + row) * ld + c8, &lds_tile[(ri * 32 + row) * 64 + c8]);
}

// the shared 128x128 MFMA inner step over one BK=64 LDS tile pair
__device__ __forceinline__ void mfma_block(const u16* As, const u16* Bs, f32x4 acc[4][4],
                                           int wm, int wn, int ln, int quad) {
#pragma unroll
  for (int ks = 0; ks < 2; ks++) {
    bf16x8 af[4], bf[4];
#pragma unroll
    for (int mt = 0; mt < 4; mt++)
      af[mt] = *(const bf16x8*)&As[(wm * 64 + mt * 16 + ln) * 64 + ks * 32 + quad * 8];
#pragma unroll
    for (int nt = 0; nt < 4; nt++)
      bf[nt] = *(const bf16x8*)&Bs[(wn * 64 + nt * 16 + ln) * 64 + ks * 32 + quad * 8];
#pragma unroll
    for (int mt = 0; mt < 4; mt++)
#pragma unroll
      for (int nt = 0; nt < 4; nt++)
        acc[mt][nt] = __builtin_amdgcn_mfma_f32_16x16x32_bf16(af[mt], bf[nt], acc[mt][nt], 0, 0, 0);
  }
}

// ---------------- kernel 1: zero out + counters ----------------
__global__ void zero_kernel(float4* __restrict__ o4, int n4,
                            int* __restrict__ cnt, float* __restrict__ probsum) {
  int i = blockIdx.x * 256 + threadIdx.x;
  if (i < n4) o4[i] = make_float4(0.f, 0.f, 0.f, 0.f);
  if (i < NE) cnt[i] = 0;
  if (i >= NE && i < NE + NE * 64) probsum[i - NE] = 0.f;
}

// ---------------- kernel 2: primitive-bank softmax + top-4 ----------------
__global__ void compose_meta(const float* __restrict__ fc1, const float* __restrict__ fc2,
                             float* __restrict__ sw1, int* __restrict__ idx1,
                             float* __restrict__ sw2, int* __restrict__ idx2) {
  int tid = threadIdx.x;
  if (tid >= 16) return;
  const float* src = (tid < 8) ? fc1 : fc2;
  float* sw = (tid < 8) ? sw1 : sw2;
  int*  idx = (tid < 8) ? idx1 : idx2;
  int e = tid & 7;
  float wv[NP];
  float mx = -1e30f;
  for (int p = 0; p < NP; p++) { wv[p] = src[e * NP + p]; mx = fmaxf(mx, wv[p]); }
  float sum = 0.f;
  for (int p = 0; p < NP; p++) { wv[p] = __expf(wv[p] - mx); sum += wv[p]; }
  float inv = 1.f / sum;
  for (int p = 0; p < NP; p++) wv[p] *= inv;
  float tw[KP]; int ti[KP];
  for (int k = 0; k < KP; k++) {
    int best = 0; float bv = -1.f;
    for (int p = 0; p < NP; p++) if (wv[p] > bv) { bv = wv[p]; best = p; }
    tw[k] = bv; ti[k] = best; wv[best] = -2.f;
  }
  float ts = tw[0] + tw[1] + tw[2] + tw[3];
  float invt = 1.f / (ts + EPSF);
  for (int k = 0; k < KP; k++) {
    sw[e * KP + k] = sqrtf(tw[k] * invt + EPSF);
    idx[e * KP + k] = ti[k];
  }
}

// ---------------- kernel 3: build composed weights, (N,K) bf16 layouts ----------------
__global__ void build_weights(const float* __restrict__ A1, const float* __restrict__ B1,
                              const float* __restrict__ A2, const float* __restrict__ B2,
                              const float* __restrict__ sw1, const int* __restrict__ idx1,
                              const float* __restrict__ sw2, const int* __restrict__ idx2,
                              u16* __restrict__ W1, u16* __restrict__ V1,
                              u16* __restrict__ W2, u16* __restrict__ V2) {
  const int S1 = NE * KR * DM;    // 1048576
  const int S2 = NE * DFF * KR;   // 4194304
  const int S3 = NE * KR * DFF;   // 4194304
  const int S4 = NE * DM * KR;    // 1048576
  int i = blockIdx.x * 256 + threadIdx.x;
  if (i >= S1 + S2 + S3 + S4) return;
  if (i < S1) {
    int d = i & (DM - 1); int kr = (i >> 9) & (KR - 1); int e = i >> 17;
    int k = kr >> 6, r = kr & 63; int p = idx1[e * 4 + k];
    W1[i] = f2bf(A1[((size_t)p * DM + d) * RANK + r] * sw1[e * 4 + k]);
  } else if (i < S1 + S2) {
    int j = i - S1;
    int kr = j & 255; int f = (j >> 8) & 2047; int e = j >> 19;
    int k = kr >> 6, r = kr & 63; int p = idx1[e * 4 + k];
    V1[j] = f2bf(B1[((size_t)p * RANK + r) * DFF + f] * sw1[e * 4 + k]);
  } else if (i < S1 + S2 + S3) {
    int j = i - S1 - S2;
    int f = j & 2047; int kr = (j >> 11) & 255; int e = j >> 19;
    int k = kr >> 6, r = kr & 63; int p = idx2[e * 4 + k];
    W2[j] = f2bf(A2[((size_t)p * DFF + f) * RANK + r] * sw2[e * 4 + k]);
  } else {
    int j = i - S1 - S2 - S3;
    int kr = j & 255; int d = (j >> 8) & 511; int e = j >> 17;
    int k = kr >> 6, r = kr & 63; int p = idx2[e * 4 + k];
    V2[j] = f2bf(B2[((size_t)p * RANK + r) * DM + d] * sw2[e * 4 + k]);
  }
}

// ---------------- kernel 4: router, token-per-lane (k-split 4) ----------------
// 256 blocks x 256 thr. Wave = 16 tokens x 4 k-slices. Wr staged once per block
// into slice-padded LDS (stride 132 floats -> 4 slice addrs hit distinct banks,
// token lanes broadcast). 2 shuffles/expert reduction; per-lane softmax/top2.
__global__ __launch_bounds__(256) void router_kernel(
    const float* __restrict__ x, const float* __restrict__ Wr,
    float* __restrict__ probsum, int* __restrict__ eidx,
    float* __restrict__ gate) {
  __shared__ float wr_s[NE * 4 * 132];   // 16896 B
  __shared__ float ps_s[NE];
  int tid = threadIdx.x;
  if (tid < NE) ps_s[tid] = 0.f;
  for (int i = tid; i < NE * DM; i += 256) {
    int e = i >> 9, k = i & 511;
    wr_s[(e * 4 + (k >> 7)) * 132 + (k & 127)] = Wr[i];
  }
  __syncthreads();
  int lane = tid & 63, wv = tid >> 6;
  int tl = lane & 15, sl = lane >> 4;
  int t = blockIdx.x * 64 + wv * 16 + tl;
  const float* xp = x + (size_t)t * DM + sl * 128;
  const float* wp = &wr_s[sl * 132];
  float acc[NE];
#pragma unroll
  for (int e = 0; e < NE; e++) acc[e] = 0.f;
  for (int c = 0; c < 32; c++) {
    float4 xv = *(const float4*)(xp + c * 4);
#pragma unroll
    for (int e = 0; e < NE; e++) {
      float4 w4 = *(const float4*)(wp + e * 4 * 132 + c * 4);
      acc[e] += xv.x * w4.x + xv.y * w4.y + xv.z * w4.z + xv.w * w4.w;
    }
  }
#pragma unroll
  for (int e = 0; e < NE; e++) {
    acc[e] += __shfl_xor(acc[e], 16, 64);
    acc[e] += __shfl_xor(acc[e], 32, 64);
  }
  if (sl == 0) {
    float mx = acc[0];
#pragma unroll
    for (int e = 1; e < NE; e++) mx = fmaxf(mx, acc[e]);
    float pe[NE]; float sum = 0.f;
#pragma unroll
    for (int e = 0; e < NE; e++) { pe[e] = __expf(acc[e] - mx); sum += pe[e]; }
    float inv = 1.f / sum;
#pragma unroll
    for (int e = 0; e < NE; e++) pe[e] *= inv;
    int i0 = 0;
#pragma unroll
    for (int e = 1; e < NE; e++) if (pe[e] > pe[i0]) i0 = e;
    int i1 = (i0 == 0) ? 1 : 0;
#pragma unroll
    for (int e = 0; e < NE; e++) if (e != i0 && pe[e] > pe[i1]) i1 = e;
    float p0 = pe[i0], p1 = pe[i1];
    float gd = 1.f / (p0 + p1 + EPSF);
    eidx[t] = i0 | (i1 << 3);
    gate[i0 * T_TOK + t] = p0 * gd;
    gate[i1 * T_TOK + t] = p1 * gd;
#pragma unroll
    for (int e = 0; e < NE; e++) atomicAdd(&ps_s[e], pe[e]);
  }
  __syncthreads();
  if (tid < NE) atomicAdd(&probsum[tid * 64 + (blockIdx.x & 63)], ps_s[tid]);
}

// ---------------- kernel 4b: scatter (block-aggregated cnt) ----------------
__global__ void scatter_kernel(const int* __restrict__ eidx,
                               int* __restrict__ cnt, int* __restrict__ perm) {
  __shared__ int hist[NE], base[NE];
  int tid = threadIdx.x;
  if (tid < NE) hist[tid] = 0;
  __syncthreads();
  int t = blockIdx.x * 256 + tid;
  int pk = eidx[t];
  int e0 = pk & 7, e1 = (pk >> 3) & 7;
  int p0 = atomicAdd(&hist[e0], 1);
  int p1 = atomicAdd(&hist[e1], 1);
  __syncthreads();
  if (tid < NE) base[tid] = atomicAdd(&cnt[tid], hist[tid]);
  __syncthreads();
  perm[e0 * T_TOK + base[e0] + p0] = t;
  perm[e1 * T_TOK + base[e1] + p1] = t;
}

// ---------------- kernel 5: aux loss (one wave) ----------------
__global__ void aux_kernel(const int* __restrict__ cnt, const float* __restrict__ probsum,
                           float* __restrict__ aux_out) {
  int lane = threadIdx.x;
  if (lane >= 64) return;
  float s[NE];
#pragma unroll
  for (int e = 0; e < NE; e++) {
    float v = probsum[e * 64 + lane];
#pragma unroll
    for (int off = 32; off > 0; off >>= 1) v += __shfl_xor(v, off, 64);
    s[e] = v;
  }
  if (lane == 0) {
    float c[NE]; float cs = 0.f;
    for (int e = 0; e < NE; e++) { c[e] = (float)cnt[e]; cs += c[e]; }
    float aux = 0.f;
    for (int e = 0; e < NE; e++)
      aux += (c[e] / (cs + EPSF)) * (s[e] / (float)T_TOK);
    *aux_out = (float)NE * aux;
  }
}

// ================= split-pipeline GEMM kernels =================
// K1: u[slot,256] = bf16( gather(x) @ A1c )          B = W1 (256,512)
__global__ __launch_bounds__(256) void k1_u(
    const float* __restrict__ x, const int* __restrict__ cnt,
    const int* __restrict__ perm, const u16* __restrict__ W1,
    u16* __restrict__ u) {
  __shared__ __align__(16) u16 As[8192], Bs[8192];
  __shared__ int tok_s[128];
  int bid = blockIdx.x;
  int ntile = bid & 1, gm = bid >> 1;
  int e = gm / MT_E, mt = gm % MT_E;
  int m0 = mt << 7;
  int cntE = cnt[e];
  if (m0 >= cntE) return;
  int tid = threadIdx.x;
  if (tid < 128) {
    int mm = m0 + tid; if (mm > cntE - 1) mm = cntE - 1;
    tok_s[tid] = perm[e * T_TOK + mm];
  }
  __syncthreads();
  const u16* Bbase = W1 + (size_t)e * KR * DM + (size_t)(ntile * 128) * DM;
  int wv = tid >> 6, lane = tid & 63;
  int wm = wv >> 1, wn = wv & 1, ln = lane & 15, quad = lane >> 4;
  f32x4 acc[4][4];
#pragma unroll
  for (int a = 0; a < 4; a++)
#pragma unroll
    for (int b = 0; b < 4; b++) acc[a][b] = (f32x4){0.f, 0.f, 0.f, 0.f};
  for (int k0 = 0; k0 < DM; k0 += 64) {
    for (int i = tid; i < 2048; i += 256) {
      int row = i >> 4, c4 = i & 15;
      float4 v = *(const float4*)(x + (size_t)tok_s[row] * DM + k0 + c4 * 4);
      u16x4v o; o[0] = f2bf(v.x); o[1] = f2bf(v.y); o[2] = f2bf(v.z); o[3] = f2bf(v.w);
      *(u16x4v*)&As[row * 64 + c4 * 4] = o;
    }
    stage_tile(Bbase + k0, DM, Bs, tid);
    __syncthreads();
    mfma_block(As, Bs, acc, wm, wn, ln, quad);
    __syncthreads();
  }
  int slot0 = e * CAP + m0;
#pragma unroll
  for (int mt2 = 0; mt2 < 4; mt2++)
#pragma unroll
    for (int nt = 0; nt < 4; nt++)
#pragma unroll
      for (int r = 0; r < 4; r++) {
        int row = wm * 64 + mt2 * 16 + quad * 4 + r;
        int col = ntile * 128 + wn * 64 + nt * 16 + ln;
        u[(size_t)(slot0 + row) * KR + col] = f2bf(acc[mt2][nt][r]);
      }
}

// K2 (chunk c): h[slot, 512] = gelu( u @ B1c[:, c*512 : c*512+512] )   B = V1
__global__ __launch_bounds__(256) void k2_h(
    const u16* __restrict__ u, const int* __restrict__ cnt,
    const u16* __restrict__ V1, u16* __restrict__ h, int c) {
  __shared__ __align__(16) u16 As[8192], Bs[8192];
  int bid = blockIdx.x;
  int ntile = bid & 3, gm = bid >> 2;
  int e = gm / MT_E, mt = gm % MT_E;
  int m0 = mt << 7;
  int cntE = cnt[e];
  if (m0 >= cntE) return;
  int tid = threadIdx.x;
  int slot0 = e * CAP + m0;
  const u16* Abase = u + (size_t)slot0 * KR;
  const u16* Bbase = V1 + (size_t)e * DFF * KR + (size_t)(c * 512 + ntile * 128) * KR;
  int wv = tid >> 6, lane = tid & 63;
  int wm = wv >> 1, wn = wv & 1, ln = lane & 15, quad = lane >> 4;
  f32x4 acc[4][4];
#pragma unroll
  for (int a = 0; a < 4; a++)
#pragma unroll
    for (int b = 0; b < 4; b++) acc[a][b] = (f32x4){0.f, 0.f, 0.f, 0.f};
  for (int k0 = 0; k0 < KR; k0 += 64) {
    stage_tile(Abase + k0, KR, As, tid);
    stage_tile(Bbase + k0, KR, Bs, tid);
    __syncthreads();
    mfma_block(As, Bs, acc, wm, wn, ln, quad);
    __syncthreads();
  }
#pragma unroll
  for (int mt2 = 0; mt2 < 4; mt2++)
#pragma unroll
    for (int nt = 0; nt < 4; nt++)
#pragma unroll
      for (int r = 0; r < 4; r++) {
        int row = wm * 64 + mt2 * 16 + quad * 4 + r;
        int col = ntile * 128 + wn * 64 + nt * 16 + ln;
        float v = acc[mt2][nt][r];
        float s = 1.f / (1.f + __expf(-1.702f * v));
        h[(size_t)(slot0 + row) * 512 + col] = f2bf(v * s);
      }
}

// K3 (chunk c): t[slot,256] (+)= h @ A2c[c*512 : , :]    B = W2 cols c*512..
__global__ __launch_bounds__(256) void k3_t(
    const u16* __restrict__ h, const int* __restrict__ cnt,
    const u16* __restrict__ W2, float* __restrict__ t, int c, int beta) {
  __shared__ __align__(16) u16 As[8192], Bs[8192];
  int bid = blockIdx.x;
  int ntile = bid & 1, gm = bid >> 1;
  int e = gm / MT_E, mt = gm % MT_E;
  int m0 = mt << 7;
  int cntE = cnt[e];
  if (m0 >= cntE) return;
  int tid = threadIdx.x;
  int slot0 = e * CAP + m0;
  const u16* Abase = h + (size_t)slot0 * 512;
  const u16* Bbase = W2 + (size_t)e * KR * DFF + (size_t)(ntile * 128) * DFF + c * 512;
  int wv = tid >> 6, lane = tid & 63;
  int wm = wv >> 1, wn = wv & 1, ln = lane & 15, quad = lane >> 4;
  f32x4 acc[4][4];
#pragma unroll
  for (int a = 0; a < 4; a++)
#pragma unroll
    for (int b = 0; b < 4; b++) acc[a][b] = (f32x4){0.f, 0.f, 0.f, 0.f};
  for (int k0 = 0; k0 < 512; k0 += 64) {
    stage_tile(Abase + k0, 512, As, tid);
    stage_tile(Bbase + k0, DFF, Bs, tid);
    __syncthreads();
    mfma_block(As, Bs, acc, wm, wn, ln, quad);
    __syncthreads();
  }
#pragma unroll
  for (int mt2 = 0; mt2 < 4; mt2++)
#pragma unroll
    for (int nt = 0; nt < 4; nt++)
#pragma unroll
      for (int r = 0; r < 4; r++) {
        int row = wm * 64 + mt2 * 16 + quad * 4 + r;
        int col = ntile * 128 + wn * 64 + nt * 16 + ln;
        float* tp = t + (size_t)(slot0 + row) * KR + col;
        float v = acc[mt2][nt][r];
        if (beta) v += *tp;
        *tp = v;
      }
}

// K4: y = t @ B2c, scatter out[token] += gate * y      B = V2 (512,256)
__global__ __launch_bounds__(256) void k4_y(
    const float* __restrict__ t, const int* __restrict__ cnt,
    const int* __restrict__ perm, const float* __restrict__ gate,
    const u16* __restrict__ V2, float* __restrict__ out) {
  __shared__ __align__(16) u16 As[8192], Bs[8192];
  __shared__ int tok_s[128];
  __shared__ float g_s[128];
  int bid = blockIdx.x;
  int ntile = bid & 3, gm = bid >> 2;
  int e = gm / MT_E, mt = gm % MT_E;
  int m0 = mt << 7;
  int cntE = cnt[e];
  if (m0 >= cntE) return;
  int tid = threadIdx.x;
  if (tid < 128) {
    int mm = m0 + tid; if (mm > cntE - 1) mm = cntE - 1;
    int tk = perm[e * T_TOK + mm];
    tok_s[tid] = tk;
    g_s[tid] = gate[e * T_TOK + tk];
  }
  __syncthreads();
  int slot0 = e * CAP + m0;
  const float* Abase = t + (size_t)slot0 * KR;
  const u16* Bbase = V2 + (size_t)e * DM * KR + (size_t)(ntile * 128) * KR;
  int wv = tid >> 6, lane = tid & 63;
  int wm = wv >> 1, wn = wv & 1, ln = lane & 15, quad = lane >> 4;
  f32x4 acc[4][4];
#pragma unroll
  for (int a = 0; a < 4; a++)
#pragma unroll
    for (int b = 0; b < 4; b++) acc[a][b] = (f32x4){0.f, 0.f, 0.f, 0.f};
  for (int k0 = 0; k0 < KR; k0 += 64) {
    for (int i = tid; i < 2048; i += 256) {
      int row = i >> 4, c4 = i & 15;
      float4 v = *(const float4*)(Abase + (size_t)row * KR + k0 + c4 * 4);
      u16x4v o; o[0] = f2bf(v.x); o[1] = f2bf(v.y); o[2] = f2bf(v.z); o[3] = f2bf(v.w);
      *(u16x4v*)&As[row * 64 + c4 * 4] = o;
    }
    stage_tile(Bbase + k0, KR, Bs, tid);
    __syncthreads();
    mfma_block(As, Bs, acc, wm, wn, ln, quad);
    __syncthreads();
  }
#pragma unroll
  for (int mt2 = 0; mt2 < 4; mt2++)
#pragma unroll
    for (int nt = 0; nt < 4; nt++)
#pragma unroll
      for (int r = 0; r < 4; r++) {
        int row = wm * 64 + mt2 * 16 + quad * 4 + r;
        if (m0 + row < cntE) {
          int col = ntile * 128 + wn * 64 + nt * 16 + ln;
          atomicAdd(out + (size_t)tok_s[row] * DM + col, acc[mt2][nt][r] * g_s[row]);
        }
      }
}

// ---------------- launch ----------------
extern "C" void kernel_launch(void* const* d_in, const int* in_sizes, int n_in,
                              void* d_out, int out_size, void* d_ws, size_t ws_size,
                              hipStream_t stream) {
  const float* x   = (const float*)d_in[0];
  const float* Wr  = (const float*)d_in[1];
  const float* fc1 = (const float*)d_in[2];
  const float* fc2 = (const float*)d_in[3];
  const float* A1  = (const float*)d_in[4];
  const float* B1  = (const float*)d_in[5];
  const float* A2  = (const float*)d_in[6];
  const float* B2  = (const float*)d_in[7];
  float* out = (float*)d_out;

  char* ws = (char*)d_ws;
  float* sw1     = (float*)(ws + 0);
  int*   idx1    = (int*)(ws + 512);
  float* sw2     = (float*)(ws + 1024);
  int*   idx2    = (int*)(ws + 1536);
  int*   cnt     = (int*)(ws + 2048);
  float* probsum = (float*)(ws + 2560);         // 8 x 64 slots = 2048 B
  int*   eidx    = (int*)(ws + 8192);           // 16384 int = 64 KB
  float* gate    = (float*)(ws + 8192 + 65536);           // 8 x 16384 f32
  int*   perm    = (int*)(ws + 8192 + 65536 + 524288);    // 8 x 16384 int
  u16*   W1      = (u16*)(ws + 8192 + 65536 + 2 * 524288);
  u16*   V1      = W1 + 1048576;
  u16*   W2      = V1 + 4194304;
  u16*   V2      = W2 + 4194304;
  char*  endW    = (char*)(V2 + 1048576);
  u16*   u_buf   = (u16*)endW;                          // 49152 x 256 bf16
  u16*   h_buf   = (u16*)(endW + 25165824);             // 49152 x 512 bf16
  float* t_buf   = (float*)(endW + 25165824 + 50331648);// 49152 x 256 f32
  const size_t WS_SPLIT_NEED = (size_t)(endW - ws) + 25165824ULL + 50331648ULL + 50331648ULL;

  int n4 = out_size >> 2;
  zero_kernel<<<(n4 + 255) / 256, 256, 0, stream>>>((float4*)d_out, n4, cnt, probsum);
  compose_meta<<<1, 64, 0, stream>>>(fc1, fc2, sw1, idx1, sw2, idx2);
  build_weights<<<40960, 256, 0, stream>>>(A1, B1, A2, B2, sw1, idx1, sw2, idx2, W1, V1, W2, V2);
  router_kernel<<<T_TOK / 64, 256, 0, stream>>>(x, Wr, probsum, eidx, gate);
  scatter_kernel<<<T_TOK / 256, 256, 0, stream>>>(eidx, cnt, perm);
  aux_kernel<<<1, 64, 0, stream>>>(cnt, probsum, out + (out_size - 1));

  if (ws_size >= WS_SPLIT_NEED) {
    k1_u<<<2 * NE * MT_E, 256, 0, stream>>>(x, cnt, perm, W1, u_buf);
    for (int c = 0; c < 4; c++) {
      k2_h<<<4 * NE * MT_E, 256, 0, stream>>>(u_buf, cnt, V1, h_buf, c);
      k3_t<<<2 * NE * MT_E, 256, 0, stream>>>(h_buf, cnt, W2, t_buf, c, c > 0 ? 1 : 0);
    }
    k4_y<<<4 * NE * MT_E, 256, 0, stream>>>(t_buf, cnt, perm, gate, V2, out);
  }
}